// Round 9
// baseline (439.805 us; speedup 1.0000x reference)
//
#include <hip/hip_runtime.h>
#include <hip/hip_bf16.h>

typedef unsigned short u16;
typedef __attribute__((ext_vector_type(4))) float f32x4;
typedef __attribute__((ext_vector_type(8))) short short8;

// B=8 QLEN=256 D=1024 H=16 HD=64 FFN=4096 PAGE=16 KV_TOTAL=4096 P=256
// PREFIX=3840 SCALE=0.125
#define MODE_QKV 0
#define MODE_WO  1
#define MODE_F1  2
#define MODE_F2  3

__device__ inline u16 f2bf(float f) {
    __hip_bfloat16 h = __float2bfloat16(f);
    return *(u16*)&h;
}

typedef __attribute__((address_space(3))) unsigned int lds_u32_t;
typedef const __attribute__((address_space(1))) unsigned int glb_u32_t;
__device__ inline void gload16(const u16* g, u16* l) {
    __builtin_amdgcn_global_load_lds((glb_u32_t*)(const void*)g,
                                     (lds_u32_t*)(void*)l, 16, 0, 0);
}

// ---------------- prep: Wq/Wk/Wv transposes + x cast ----------------
__global__ __launch_bounds__(256) void prep_wx(
    const float* __restrict__ Wq, const float* __restrict__ Wk,
    const float* __restrict__ Wv, const float* __restrict__ x,
    u16* __restrict__ WqkvT, u16* __restrict__ xb) {
    int bid = blockIdx.x;
    int tid = threadIdx.x;
    int tx = tid & 31, ty = tid >> 5;
    if (bid >= 3072) {
        int i = (bid - 3072) * 256 + tid;
        const float4* p = (const float4*)(x + (size_t)i * 8);
        float4 a = p[0], b = p[1];
        u16 t[8] = {f2bf(a.x), f2bf(a.y), f2bf(a.z), f2bf(a.w),
                    f2bf(b.x), f2bf(b.y), f2bf(b.z), f2bf(b.w)};
        *(uint4*)(xb + (size_t)i * 8) = *(const uint4*)t;
        return;
    }
    int m = bid >> 10, r = bid & 1023;
    const float* src = (m == 0) ? Wq : (m == 1) ? Wk : Wv;
    u16* dst = WqkvT + (size_t)m * 1024 * 1024;
    __shared__ float t[32][33];
    int n0 = (r & 31) * 32, k0 = (r >> 5) * 32;
#pragma unroll
    for (int j = 0; j < 32; j += 8)
        t[ty + j][tx] = src[(size_t)(k0 + ty + j) * 1024 + n0 + tx];
    __syncthreads();
#pragma unroll
    for (int j = 0; j < 32; j += 8)
        dst[(size_t)(n0 + ty + j) * 1024 + k0 + tx] = f2bf(t[tx][ty + j]);
}

// ---------------- layer norm over rows of 1024 ----------------
__global__ __launch_bounds__(256) void ln_row(const float* __restrict__ in,
                                              const float* __restrict__ g,
                                              const float* __restrict__ be,
                                              float* __restrict__ outf,
                                              u16* __restrict__ outb) {
    int row = blockIdx.x;
    int tid = threadIdx.x;
    const float* p = in + (size_t)row * 1024 + tid * 4;
    float4 v = *(const float4*)p;
    float s = v.x + v.y + v.z + v.w;
#pragma unroll
    for (int m = 1; m < 64; m <<= 1) s += __shfl_xor(s, m, 64);
    __shared__ float red1[4], red2[4];
    int w = tid >> 6;
    if ((tid & 63) == 0) red1[w] = s;
    __syncthreads();
    float mu = (red1[0] + red1[1] + red1[2] + red1[3]) * (1.0f / 1024.0f);
    float dx = v.x - mu, dy = v.y - mu, dz = v.z - mu, dw = v.w - mu;
    float q = dx * dx + dy * dy + dz * dz + dw * dw;
#pragma unroll
    for (int m = 1; m < 64; m <<= 1) q += __shfl_xor(q, m, 64);
    if ((tid & 63) == 0) red2[w] = q;
    __syncthreads();
    float var = (red2[0] + red2[1] + red2[2] + red2[3]) * (1.0f / 1024.0f);
    float rs = rsqrtf(var + 1e-5f);
    int c = tid * 4;
    float o0 = dx * rs * g[c + 0] + be[c + 0];
    float o1 = dy * rs * g[c + 1] + be[c + 1];
    float o2 = dz * rs * g[c + 2] + be[c + 2];
    float o3 = dw * rs * g[c + 3] + be[c + 3];
    if (outf) {
        float4 o; o.x = o0; o.y = o1; o.z = o2; o.w = o3;
        *(float4*)(outf + (size_t)row * 1024 + c) = o;
    }
    if (outb) {
        u16 t[4] = {f2bf(o0), f2bf(o1), f2bf(o2), f2bf(o3)};
        *(uint2*)&outb[(size_t)row * 1024 + c] = *(const uint2*)t;
    }
}

// ---------------- 128x128 GEMM body (WO/FFN only) ----------------
template <int MODE>
__device__ __forceinline__ void gemm_body(
    u16* As, u16* Bs, int m0, int n0,
    const u16* __restrict__ A, const u16* __restrict__ Bt, int K, int N,
    const float* __restrict__ bias0, const float* __restrict__ aux,
    float* __restrict__ o0, float* __restrict__ o1, u16* __restrict__ ob) {
    int tid = threadIdx.x;
    int l = tid & 63, w = tid >> 6;
    int wr = w >> 1, wc = w & 1;
    int lr = l & 15, lg = l >> 4;
    int lrow8 = l >> 3;
    int scol = ((l & 7) ^ lrow8) << 3;
    f32x4 acc[4][4] = {};
    for (int kb = 0; kb < K; kb += 64) {
#pragma unroll
        for (int p = 0; p < 4; ++p) {
            int chunk = p * 4 + w;
            int r = chunk * 8 + lrow8;
            gload16(&A[(size_t)(m0 + r) * K + kb + scol], &As[chunk * 512]);
            gload16(&Bt[(size_t)(n0 + r) * K + kb + scol], &Bs[chunk * 512]);
        }
        __syncthreads();
#pragma unroll
        for (int kk = 0; kk < 2; ++kk) {
            short8 a[4], b[4];
            int c0 = kk * 32 + lg * 8;
#pragma unroll
            for (int mi = 0; mi < 4; mi++) {
                int row = wr * 64 + mi * 16 + lr;
                a[mi] = *(const short8*)&As[row * 64 + (c0 ^ ((row & 7) << 3))];
            }
#pragma unroll
            for (int ni = 0; ni < 4; ni++) {
                int row = wc * 64 + ni * 16 + lr;
                b[ni] = *(const short8*)&Bs[row * 64 + (c0 ^ ((row & 7) << 3))];
            }
#pragma unroll
            for (int mi = 0; mi < 4; mi++)
#pragma unroll
                for (int ni = 0; ni < 4; ni++)
                    acc[mi][ni] = __builtin_amdgcn_mfma_f32_16x16x32_bf16(
                        a[mi], b[ni], acc[mi][ni], 0, 0, 0);
        }
        __syncthreads();
    }
#pragma unroll
    for (int mi = 0; mi < 4; mi++) {
#pragma unroll
        for (int ni = 0; ni < 4; ni++) {
#pragma unroll
            for (int r = 0; r < 4; r++) {
                int row = m0 + wr * 64 + mi * 16 + lg * 4 + r;
                int col = n0 + wc * 64 + ni * 16 + lr;
                float v = acc[mi][ni][r];
                if constexpr (MODE == MODE_WO) {
                    o0[(size_t)row * N + col] = v + bias0[col] + aux[(size_t)row * N + col];
                } else if constexpr (MODE == MODE_F1) {
                    float t = v + bias0[col];
                    ob[(size_t)row * N + col] = f2bf(fmaxf(t, 0.0f));
                } else {
                    float t = v + bias0[col];
                    o0[(size_t)row * N + col] = t;
                    o1[(size_t)row * N + col] = t + aux[(size_t)row * N + col];
                }
            }
        }
    }
}

template <int MODE>
__global__ __launch_bounds__(256) void gemm_nt(
    const u16* __restrict__ A, const u16* __restrict__ Bt, int K, int N, int gx,
    const float* __restrict__ bias0, const float* __restrict__ aux,
    float* __restrict__ o0, float* __restrict__ o1, u16* __restrict__ ob) {
    __shared__ __align__(16) u16 smem[128 * 64 * 2];
    int bid = blockIdx.x;
    gemm_body<MODE>(smem, smem + 128 * 64, (bid / gx) * 128, (bid % gx) * 128,
                    A, Bt, K, N, bias0, aux, o0, o1, ob);
}

// ---- mega: low-VGPR fusion. Block id interleave: bid%12==0 -> QKV gemm64 (1536),
// ---- else rest = prefix single-read (7680) then Wo/W1/W2 transposes (9216).
__global__ __launch_bounds__(256, 7) void mega_prep(
    const u16* __restrict__ xb, const u16* __restrict__ WqkvT,
    const float* __restrict__ bq, const float* __restrict__ bk,
    const float* __restrict__ bv,
    float* __restrict__ out_pt, u16* __restrict__ qbuf,
    u16* __restrict__ Kbf, u16* __restrict__ Vtbf,
    const float* __restrict__ pgt, const int* __restrict__ kvidx,
    const float* __restrict__ Wo, const float* __restrict__ W1,
    const float* __restrict__ W2,
    u16* __restrict__ WoT, u16* __restrict__ W1T, u16* __restrict__ W2T) {
    __shared__ __align__(16) u16 smem[64 * 68 * 2]; // 17408B: gemm needs 16384, prefix 17408
    int bid = blockIdx.x;
    int tid = threadIdx.x;
    int rmod = bid % 12, q12 = bid / 12;
    if (rmod == 0) {
        // ---- QKV GEMM, 64x64 tile, BK=64 (lean VGPR) ----
        u16* As = smem;              // 64*64
        u16* Bs = smem + 4096;       // 64*64
        int m0 = (q12 / 48) * 64, n0 = (q12 % 48) * 64;
        int l = tid & 63, w = tid >> 6;
        int lr = l & 15, lg = l >> 4;
        int lrow8 = l >> 3;
        int scol = ((l & 7) ^ lrow8) << 3;
        f32x4 acc[4] = {};
        for (int kb = 0; kb < 1024; kb += 64) {
#pragma unroll
            for (int j = 0; j < 2; ++j) {
                int chunk = w * 2 + j;
                int r = chunk * 8 + lrow8;
                gload16(&xb[(size_t)(m0 + r) * 1024 + kb + scol], &As[chunk * 512]);
                gload16(&WqkvT[(size_t)(n0 + r) * 1024 + kb + scol], &Bs[chunk * 512]);
            }
            __syncthreads();
#pragma unroll
            for (int kk = 0; kk < 2; ++kk) {
                int c0 = kk * 32 + lg * 8;
                int arow = w * 16 + lr;
                short8 a = *(const short8*)&As[arow * 64 + (c0 ^ ((lr & 7) << 3))];
#pragma unroll
                for (int nt = 0; nt < 4; nt++) {
                    int brow = nt * 16 + lr;
                    short8 b = *(const short8*)&Bs[brow * 64 + (c0 ^ ((lr & 7) << 3))];
                    acc[nt] = __builtin_amdgcn_mfma_f32_16x16x32_bf16(a, b, acc[nt], 0, 0, 0);
                }
            }
            __syncthreads();
        }
#pragma unroll
        for (int nt = 0; nt < 4; nt++) {
#pragma unroll
            for (int r = 0; r < 4; r++) {
                int row = m0 + w * 16 + lg * 4 + r;
                int col = n0 + nt * 16 + lr;
                float v = acc[nt][r];
                int sel = col >> 10, c = col & 1023;
                int b = row >> 8, ii = row & 255;
                int h = (c >> 6), hd = c & 63;
                if (sel == 0) {
                    qbuf[(size_t)row * 1024 + c] = f2bf((v + bq[c]) * 0.125f);
                } else if (sel == 1) {
                    float val = v + bk[c];
                    int page = kvidx[b * 256 + 240 + (ii >> 4)];
                    out_pt[(size_t)page * 32768 + (size_t)(ii & 15) * 1024 + c] = val;
                    Kbf[((size_t)(b * 16 + h) * 4096 + 3840 + ii) * 64 + hd] = f2bf(val);
                } else {
                    float val = v + bv[c];
                    int page = kvidx[b * 256 + 240 + (ii >> 4)];
                    out_pt[(size_t)page * 32768 + 16384 + (size_t)(ii & 15) * 1024 + c] = val;
                    Vtbf[((size_t)(b * 16 + h) * 64 + hd) * 4096 + 3840 + ii] = f2bf(val);
                }
            }
        }
        return;
    }
    int rest = q12 * 11 + (rmod - 1);   // [0, 16896)
    if (rest < 7680) {
        // ---- prefix: ONE pgt read -> f32 copy + bf16 K (row-major) + bf16 V^T ----
        int tile = rest % 60, rr2 = rest / 60;
        int h = rr2 & 15, b = rr2 >> 4;
        int T0 = tile * 64;
        int rr = tid >> 4;   // 0..15 token-in-page
        int hdq = tid & 15;  // hd quad
        u16* vt = smem;      // [64][68]
        size_t kdst_base = ((size_t)(b * 16 + h) * 4096 + T0) * 64;
#pragma unroll
        for (int p = 0; p < 4; ++p) {
            int i = p * 16 + rr;
            int page = kvidx[b * 256 + (T0 >> 4) + p];
            size_t src = (size_t)page * 32768 + (size_t)rr * 1024 + h * 64 + hdq * 4;
            float4 kf = *(const float4*)(pgt + src);
            *(float4*)(out_pt + src) = kf;
            u16 kb4[4] = {f2bf(kf.x), f2bf(kf.y), f2bf(kf.z), f2bf(kf.w)};
            *(uint2*)&Kbf[kdst_base + (size_t)i * 64 + hdq * 4] = *(const uint2*)kb4;
            float4 vf = *(const float4*)(pgt + src + 16384);
            *(float4*)(out_pt + src + 16384) = vf;
            u16 vb4[4] = {f2bf(vf.x), f2bf(vf.y), f2bf(vf.z), f2bf(vf.w)};
            *(uint2*)&vt[i * 68 + hdq * 4] = *(const uint2*)vb4;
        }
        __syncthreads();
        size_t vdst_base = (size_t)(b * 16 + h) * 64 * 4096 + T0;
#pragma unroll
        for (int p = 0; p < 4; ++p) {
            int hd = p * 16 + rr;
            u16 o[4];
#pragma unroll
            for (int j = 0; j < 4; ++j) o[j] = vt[(hdq * 4 + j) * 68 + hd];
            *(uint2*)&Vtbf[vdst_base + (size_t)hd * 4096 + hdq * 4] = *(const uint2*)o;
        }
        return;
    }
    // ---- Wo/W1/W2 transposes (consumed post-attention) ----
    int wb = rest - 7680;
    const float* src; u16* dst; int K, N, bx, by;
    if (wb < 1024) {
        bx = wb & 31; by = wb >> 5; K = 1024; N = 1024; src = Wo; dst = WoT;
    } else if (wb < 5120) {
        int r = wb - 1024; bx = r & 127; by = r >> 7; K = 1024; N = 4096; src = W1; dst = W1T;
    } else {
        int r = wb - 5120; bx = r & 31; by = r >> 5; K = 4096; N = 1024; src = W2; dst = W2T;
    }
    float* t = (float*)smem; // [32][33]
    int tx = tid & 31, ty = tid >> 5;
    int n0 = bx * 32, k0 = by * 32;
#pragma unroll
    for (int j = 0; j < 32; j += 8)
        t[(ty + j) * 33 + tx] = src[(size_t)(k0 + ty + j) * N + n0 + tx];
    __syncthreads();
#pragma unroll
    for (int j = 0; j < 32; j += 8)
        dst[(size_t)(n0 + ty + j) * K + k0 + tx] = f2bf(t[tx * 33 + ty + j]);
}

// ---------------- attention: single-buffer + reg prefetch, KV-split x4 ----------------
__global__ __launch_bounds__(512) void attn_kernel(const u16* __restrict__ qb,
                                                   const u16* __restrict__ Kbf,
                                                   const u16* __restrict__ Vtbf,
                                                   float* __restrict__ pOct,
                                                   float* __restrict__ pL) {
    __shared__ u16 Ks[64 * 64];
    __shared__ u16 Vt[64 * 64];
    __shared__ u16 Ps[8][16 * 64];
    int bid = blockIdx.x;
    int tid = threadIdx.x;
    int l = tid & 63, w = tid >> 6;
    int lr = l & 15, lg = l >> 4;
    int x = bid & 7, qt = x >> 2, split = x & 3;
    int h = (bid >> 3) & 15, b = bid >> 7;

    int qrow = qt * 128 + w * 16 + lr;
    const u16* qptr = qb + (size_t)(b * 256 + qrow) * 1024 + h * 64 + lg * 8;
    short8 qf0 = *(const short8*)qptr;
    short8 qf1 = *(const short8*)(qptr + 32);

    const u16* kslab = Kbf + (size_t)(b * 16 + h) * 4096 * 64;
    const u16* vslab = Vtbf + (size_t)(b * 16 + h) * 64 * 4096;

    f32x4 octx[4] = {};
    f32x4 lacc = {};
    short8 ones;
#pragma unroll
    for (int j = 0; j < 8; j++) ones[j] = (short)0x3F80;

    int qbase = 3840 + qt * 128;
    int ntiles = (qbase + 128) >> 6;
    int tstart = split * 16;
    int tend = min(tstart + 16, ntiles);
    int kt0 = tstart * 64, kt1 = tend * 64;

    int srow = tid >> 3, scol8 = (tid & 7) * 8;
    int sdst = srow * 64 + (scol8 ^ ((srow & 7) << 3));
    const u16* kp = kslab + srow * 64 + scol8;
    const u16* vp = vslab + (size_t)srow * 4096 + scol8;

    uint4 kreg = *(const uint4*)(kp + (size_t)kt0 * 64);
    uint4 vreg = *(const uint4*)(vp + kt0);
    for (int kt = kt0; kt < kt1; kt += 64) {
        *(uint4*)&Ks[sdst] = kreg;
        *(uint4*)&Vt[sdst] = vreg;
        __syncthreads();
        bool hn = (kt + 64) < kt1;
        if (hn) {
            kreg = *(const uint4*)(kp + (size_t)(kt + 64) * 64);
            vreg = *(const uint4*)(vp + kt + 64);
        }
        float P[4][4];
        bool need_mask = (kt + 63 > qbase);
#pragma unroll
        for (int ni = 0; ni < 4; ni++) {
            f32x4 s = {};
            int krow = ni * 16 + lr;
            int swz = (krow & 7) << 3;
            short8 k0 = *(const short8*)&Ks[krow * 64 + ((lg * 8) ^ swz)];
            short8 k1 = *(const short8*)&Ks[krow * 64 + ((32 + lg * 8) ^ swz)];
            s = __builtin_amdgcn_mfma_f32_16x16x32_bf16(qf0, k0, s, 0, 0, 0);
            s = __builtin_amdgcn_mfma_f32_16x16x32_bf16(qf1, k1, s, 0, 0, 0);
            if (need_mask) {
                int col = kt + ni * 16 + lr;
#pragma unroll
                for (int r = 0; r < 4; r++) {
                    int q = qt * 128 + w * 16 + lg * 4 + r;
                    P[ni][r] = (col <= 3840 + q) ? __expf(s[r]) : 0.0f;
                }
            } else {
#pragma unroll
                for (int r = 0; r < 4; r++) P[ni][r] = __expf(s[r]);
            }
        }
#pragma unroll
        for (int ni = 0; ni < 4; ni++)
#pragma unroll
            for (int r = 0; r < 4; r++) {
                int prow = lg * 4 + r;
                Ps[w][prow * 64 + ((ni * 16 + lr) ^ ((prow & 7) << 3))] = f2bf(P[ni][r]);
            }
#pragma unroll
        for (int kk = 0; kk < 2; kk++) {
            int c0 = kk * 32 + lg * 8;
            short8 pf = *(const short8*)&Ps[w][lr * 64 + (c0 ^ ((lr & 7) << 3))];
            lacc = __builtin_amdgcn_mfma_f32_16x16x32_bf16(pf, ones, lacc, 0, 0, 0);
#pragma unroll
            for (int dt = 0; dt < 4; dt++) {
                int vrow = dt * 16 + lr;
                short8 vf = *(const short8*)&Vt[vrow * 64 + (c0 ^ ((vrow & 7) << 3))];
                octx[dt] = __builtin_amdgcn_mfma_f32_16x16x32_bf16(pf, vf, octx[dt], 0, 0, 0);
            }
        }
        __syncthreads();
    }
    size_t obase = (((size_t)(split * 8 + b) * 16 + h) * 256 + qt * 128) * 64;
#pragma unroll
    for (int dt = 0; dt < 4; dt++)
#pragma unroll
        for (int r = 0; r < 4; r++)
            pOct[obase + (size_t)(w * 16 + lg * 4 + r) * 64 + dt * 16 + lr] = octx[dt][r];
    if (lr == 0) {
        size_t lbase = ((size_t)(split * 8 + b) * 16 + h) * 256 + qt * 128;
#pragma unroll
        for (int r = 0; r < 4; r++) pL[lbase + w * 16 + lg * 4 + r] = lacc[r];
    }
}

// ---------------- combine partials -> ctx bf16 ----------------
__global__ __launch_bounds__(256) void attn_combine(const float* __restrict__ pOct,
                                                    const float* __restrict__ pL,
                                                    u16* __restrict__ ctxb) {
    int row = blockIdx.x;
    int b = row >> 8, q = row & 255;
    int tid = threadIdx.x;
    int h = tid >> 4, dq = (tid & 15) * 4;
    size_t stride = (size_t)128 * 256 * 64;
    size_t base = ((size_t)(b * 16 + h) * 256 + q) * 64 + dq;
    size_t lstride = 128 * 256;
    size_t lbase = (size_t)(b * 16 + h) * 256 + q;
    f32x4 s = {};
    float ls = 0.0f;
#pragma unroll
    for (int sp = 0; sp < 4; sp++) {
        f32x4 v = *(const f32x4*)(pOct + sp * stride + base);
        s += v;
        ls += pL[sp * lstride + lbase];
    }
    float inv = 1.0f / ls;
    u16 o[4] = {f2bf(s[0] * inv), f2bf(s[1] * inv), f2bf(s[2] * inv), f2bf(s[3] * inv)};
    *(uint2*)&ctxb[(size_t)row * 1024 + h * 64 + dq] = *(const uint2*)o;
}

// ---------------- launch ----------------
extern "C" void kernel_launch(void* const* d_in, const int* in_sizes, int n_in,
                              void* d_out, int out_size, void* d_ws, size_t ws_size,
                              hipStream_t stream) {
    (void)in_sizes; (void)n_in; (void)out_size; (void)ws_size;
    const float* x   = (const float*)d_in[0];
    const float* pgt = (const float*)d_in[1];
    const float* Wq  = (const float*)d_in[2];
    const float* bq  = (const float*)d_in[3];
    const float* Wk  = (const float*)d_in[4];
    const float* bk  = (const float*)d_in[5];
    const float* Wv  = (const float*)d_in[6];
    const float* bv  = (const float*)d_in[7];
    const float* Wo  = (const float*)d_in[8];
    const float* bo  = (const float*)d_in[9];
    const float* ln1g = (const float*)d_in[10];
    const float* ln1b = (const float*)d_in[11];
    const float* W1  = (const float*)d_in[12];
    const float* b1  = (const float*)d_in[13];
    const float* W2  = (const float*)d_in[14];
    const float* b2  = (const float*)d_in[15];
    const float* lnfg = (const float*)d_in[16];
    const float* lnfb = (const float*)d_in[17];
    const int* kvidx = (const int*)d_in[20];

    float* out = (float*)d_out;
    float* out_x  = out;
    float* out_lr = out + 2048 * 1024;
    float* out_pt = out + 2 * 2048 * 1024;

    char* ws = (char*)d_ws;
    size_t off = 0;
    auto alloc = [&](size_t bytes) { void* p = ws + off; off += (bytes + 255) & ~(size_t)255; return p; };
    u16* WqkvT = (u16*)alloc((size_t)3072 * 1024 * 2);
    u16* WoT   = (u16*)alloc((size_t)1024 * 1024 * 2);
    u16* W1T   = (u16*)alloc((size_t)4096 * 1024 * 2);
    u16* W2T   = (u16*)alloc((size_t)1024 * 4096 * 2);
    u16* xb    = (u16*)alloc((size_t)2048 * 1024 * 2);
    u16* qbuf  = (u16*)alloc((size_t)2048 * 1024 * 2);
    u16* ctxb  = (u16*)alloc((size_t)2048 * 1024 * 2);
    char* regB = (char*)alloc((size_t)2 * 8 * 16 * 4096 * 64 * 2);
    u16* Kbf  = (u16*)regB;
    u16* Vtbf = (u16*)(regB + (size_t)64 * 1024 * 1024);
    float* pOct = (float*)(regB + (size_t)128 * 1024 * 1024);
    float* pL   = (float*)(regB + (size_t)162 * 1024 * 1024);
    float* t1    = (float*)regB;
    float* xln1f = (float*)(regB + (size_t)8 * 1024 * 1024);
    u16*   hb    = (u16*)(regB + (size_t)16 * 1024 * 1024);
    u16*   xln1b = (u16*)(regB + (size_t)32 * 1024 * 1024);
    float* t2 = t1;

    prep_wx<<<4096, 256, 0, stream>>>(Wq, Wk, Wv, x, WqkvT, xb);
    mega_prep<<<18432, 256, 0, stream>>>(xb, WqkvT, bq, bk, bv,
                                         out_pt, qbuf, Kbf, Vtbf, pgt, kvidx,
                                         Wo, W1, W2, WoT, W1T, W2T);
    attn_kernel<<<1024, 512, 0, stream>>>(qbuf, Kbf, Vtbf, pOct, pL);
    attn_combine<<<2048, 256, 0, stream>>>(pOct, pL, ctxb);
    gemm_nt<MODE_WO><<<128, 256, 0, stream>>>(ctxb, WoT, 1024, 1024, 8,
        bo, x, t1, nullptr, nullptr);
    ln_row<<<2048, 256, 0, stream>>>(t1, ln1g, ln1b, xln1f, xln1b);
    gemm_nt<MODE_F1><<<512, 256, 0, stream>>>(xln1b, W1T, 1024, 4096, 32,
        b1, nullptr, nullptr, nullptr, hb);
    gemm_nt<MODE_F2><<<128, 256, 0, stream>>>(hb, W2T, 4096, 1024, 8,
        b2, xln1f, out_lr, t2, nullptr);
    ln_row<<<2048, 256, 0, stream>>>(t2, lnfg, lnfb, out_x, nullptr);
}

// Round 10
// 380.281 us; speedup vs baseline: 1.1565x; 1.1565x over previous
//
#include <hip/hip_runtime.h>
#include <hip/hip_bf16.h>

typedef unsigned short u16;
typedef __attribute__((ext_vector_type(4))) float f32x4;
typedef __attribute__((ext_vector_type(8))) short short8;

// B=8 QLEN=256 D=1024 H=16 HD=64 FFN=4096 PAGE=16 KV_TOTAL=4096 P=256
// PREFIX=3840 SCALE=0.125
#define MODE_QKV 0
#define MODE_WO  1
#define MODE_F1  2
#define MODE_F2  3

__device__ inline u16 f2bf(float f) {
    __hip_bfloat16 h = __float2bfloat16(f);
    return *(u16*)&h;
}

typedef __attribute__((address_space(3))) unsigned int lds_u32_t;
typedef const __attribute__((address_space(1))) unsigned int glb_u32_t;
__device__ inline void gload16(const u16* g, u16* l) {
    __builtin_amdgcn_global_load_lds((glb_u32_t*)(const void*)g,
                                     (lds_u32_t*)(void*)l, 16, 0, 0);
}

// ---------------- prep: Wq/Wk/Wv transposes + x cast ----------------
__global__ __launch_bounds__(256) void prep_wx(
    const float* __restrict__ Wq, const float* __restrict__ Wk,
    const float* __restrict__ Wv, const float* __restrict__ x,
    u16* __restrict__ WqkvT, u16* __restrict__ xb) {
    int bid = blockIdx.x;
    int tid = threadIdx.x;
    int tx = tid & 31, ty = tid >> 5;
    if (bid >= 3072) {
        int i = (bid - 3072) * 256 + tid;
        const float4* p = (const float4*)(x + (size_t)i * 8);
        float4 a = p[0], b = p[1];
        u16 t[8] = {f2bf(a.x), f2bf(a.y), f2bf(a.z), f2bf(a.w),
                    f2bf(b.x), f2bf(b.y), f2bf(b.z), f2bf(b.w)};
        *(uint4*)(xb + (size_t)i * 8) = *(const uint4*)t;
        return;
    }
    int m = bid >> 10, r = bid & 1023;
    const float* src = (m == 0) ? Wq : (m == 1) ? Wk : Wv;
    u16* dst = WqkvT + (size_t)m * 1024 * 1024;
    __shared__ float t[32][33];
    int n0 = (r & 31) * 32, k0 = (r >> 5) * 32;
#pragma unroll
    for (int j = 0; j < 32; j += 8)
        t[ty + j][tx] = src[(size_t)(k0 + ty + j) * 1024 + n0 + tx];
    __syncthreads();
#pragma unroll
    for (int j = 0; j < 32; j += 8)
        dst[(size_t)(n0 + ty + j) * 1024 + k0 + tx] = f2bf(t[tx][ty + j]);
}

// ---------------- layer norm over rows of 1024 ----------------
__global__ __launch_bounds__(256) void ln_row(const float* __restrict__ in,
                                              const float* __restrict__ g,
                                              const float* __restrict__ be,
                                              float* __restrict__ outf,
                                              u16* __restrict__ outb) {
    int row = blockIdx.x;
    int tid = threadIdx.x;
    const float* p = in + (size_t)row * 1024 + tid * 4;
    float4 v = *(const float4*)p;
    float s = v.x + v.y + v.z + v.w;
#pragma unroll
    for (int m = 1; m < 64; m <<= 1) s += __shfl_xor(s, m, 64);
    __shared__ float red1[4], red2[4];
    int w = tid >> 6;
    if ((tid & 63) == 0) red1[w] = s;
    __syncthreads();
    float mu = (red1[0] + red1[1] + red1[2] + red1[3]) * (1.0f / 1024.0f);
    float dx = v.x - mu, dy = v.y - mu, dz = v.z - mu, dw = v.w - mu;
    float q = dx * dx + dy * dy + dz * dz + dw * dw;
#pragma unroll
    for (int m = 1; m < 64; m <<= 1) q += __shfl_xor(q, m, 64);
    if ((tid & 63) == 0) red2[w] = q;
    __syncthreads();
    float var = (red2[0] + red2[1] + red2[2] + red2[3]) * (1.0f / 1024.0f);
    float rs = rsqrtf(var + 1e-5f);
    int c = tid * 4;
    float o0 = dx * rs * g[c + 0] + be[c + 0];
    float o1 = dy * rs * g[c + 1] + be[c + 1];
    float o2 = dz * rs * g[c + 2] + be[c + 2];
    float o3 = dw * rs * g[c + 3] + be[c + 3];
    if (outf) {
        float4 o; o.x = o0; o.y = o1; o.z = o2; o.w = o3;
        *(float4*)(outf + (size_t)row * 1024 + c) = o;
    }
    if (outb) {
        u16 t[4] = {f2bf(o0), f2bf(o1), f2bf(o2), f2bf(o3)};
        *(uint2*)&outb[(size_t)row * 1024 + c] = *(const uint2*)t;
    }
}

// ---------------- GEMM body: C[M,N] = A[M,K]*Bt[N,K]^T, tile 128x128, BK=64 ----------
template <int MODE>
__device__ __forceinline__ void gemm_body(
    u16* As, u16* Bs, int m0, int n0,
    const u16* __restrict__ A, const u16* __restrict__ Bt, int K, int N,
    const float* __restrict__ bias0, const float* __restrict__ bias1,
    const float* __restrict__ bias2, const float* __restrict__ aux,
    float* __restrict__ o0, float* __restrict__ o1, u16* __restrict__ ob,
    u16* __restrict__ kbf, u16* __restrict__ vbf, const int* __restrict__ kvidx) {
    int tid = threadIdx.x;
    int l = tid & 63, w = tid >> 6;
    int wr = w >> 1, wc = w & 1;
    int lr = l & 15, lg = l >> 4;
    int lrow8 = l >> 3;
    int scol = ((l & 7) ^ lrow8) << 3;
    f32x4 acc[4][4] = {};
    for (int kb = 0; kb < K; kb += 64) {
#pragma unroll
        for (int p = 0; p < 4; ++p) {
            int chunk = p * 4 + w;
            int r = chunk * 8 + lrow8;
            gload16(&A[(size_t)(m0 + r) * K + kb + scol], &As[chunk * 512]);
            gload16(&Bt[(size_t)(n0 + r) * K + kb + scol], &Bs[chunk * 512]);
        }
        __syncthreads();
#pragma unroll
        for (int kk = 0; kk < 2; ++kk) {
            short8 a[4], b[4];
            int c0 = kk * 32 + lg * 8;
#pragma unroll
            for (int mi = 0; mi < 4; mi++) {
                int row = wr * 64 + mi * 16 + lr;
                a[mi] = *(const short8*)&As[row * 64 + (c0 ^ ((row & 7) << 3))];
            }
#pragma unroll
            for (int ni = 0; ni < 4; ni++) {
                int row = wc * 64 + ni * 16 + lr;
                b[ni] = *(const short8*)&Bs[row * 64 + (c0 ^ ((row & 7) << 3))];
            }
#pragma unroll
            for (int mi = 0; mi < 4; mi++)
#pragma unroll
                for (int ni = 0; ni < 4; ni++)
                    acc[mi][ni] = __builtin_amdgcn_mfma_f32_16x16x32_bf16(
                        a[mi], b[ni], acc[mi][ni], 0, 0, 0);
        }
        __syncthreads();
    }
#pragma unroll
    for (int mi = 0; mi < 4; mi++) {
#pragma unroll
        for (int ni = 0; ni < 4; ni++) {
#pragma unroll
            for (int r = 0; r < 4; r++) {
                int row = m0 + wr * 64 + mi * 16 + lg * 4 + r;
                int col = n0 + wc * 64 + ni * 16 + lr;
                float v = acc[mi][ni][r];
                if constexpr (MODE == MODE_QKV) {
                    int sel = col >> 10, c = col & 1023;
                    int b = row >> 8, ii = row & 255;
                    int h = (c >> 6), hd = c & 63;
                    if (sel == 0) {
                        ob[(size_t)row * 1024 + c] = f2bf((v + bias0[c]) * 0.125f);
                    } else if (sel == 1) {
                        float val = v + bias1[c];
                        int page = kvidx[b * 256 + 240 + (ii >> 4)];
                        o0[(size_t)page * 32768 + (size_t)(ii & 15) * 1024 + c] = val;
                        kbf[((size_t)(b * 16 + h) * 4096 + 3840 + ii) * 64 + hd] = f2bf(val);
                    } else {
                        float val = v + bias2[c];
                        int page = kvidx[b * 256 + 240 + (ii >> 4)];
                        o0[(size_t)page * 32768 + 16384 + (size_t)(ii & 15) * 1024 + c] = val;
                        vbf[((size_t)(b * 16 + h) * 64 + hd) * 4096 + 3840 + ii] = f2bf(val);
                    }
                } else if constexpr (MODE == MODE_WO) {
                    o0[(size_t)row * N + col] = v + bias0[col] + aux[(size_t)row * N + col];
                } else if constexpr (MODE == MODE_F1) {
                    float t = v + bias0[col];
                    ob[(size_t)row * N + col] = f2bf(fmaxf(t, 0.0f));
                } else {
                    float t = v + bias0[col];
                    o0[(size_t)row * N + col] = t;
                    o1[(size_t)row * N + col] = t + aux[(size_t)row * N + col];
                }
            }
        }
    }
}

template <int MODE>
__global__ __launch_bounds__(256) void gemm_nt(
    const u16* __restrict__ A, const u16* __restrict__ Bt, int K, int N, int gx,
    const float* __restrict__ bias0, const float* __restrict__ aux,
    float* __restrict__ o0, float* __restrict__ o1, u16* __restrict__ ob) {
    __shared__ __align__(16) u16 smem[128 * 64 * 2];
    int bid = blockIdx.x;
    gemm_body<MODE>(smem, smem + 128 * 64, (bid / gx) * 128, (bid % gx) * 128,
                    A, Bt, K, N, bias0, nullptr, nullptr, aux, o0, o1, ob,
                    nullptr, nullptr, nullptr);
}

// ---- mega: QKV GEMM [0,384) + K-prep [384,864) + V-prep [864,1344) ----
// K/V-prep: sequential-granularity single-read prefix {f32 copy + bf16 K / bf16 V^T}
__global__ __launch_bounds__(256) void mega_prep(
    const u16* __restrict__ xb, const u16* __restrict__ WqkvT,
    const float* __restrict__ bq, const float* __restrict__ bk,
    const float* __restrict__ bv,
    float* __restrict__ out_pt, u16* __restrict__ qbuf,
    u16* __restrict__ Kbf, u16* __restrict__ Vtbf,
    const float* __restrict__ pgt, const int* __restrict__ kvidx) {
    __shared__ __align__(16) u16 smem[16640]; // gemm 16384 u16; V-prep [64][260]
    int bid = blockIdx.x;
    int tid = threadIdx.x;
    if (bid < 384) {
        gemm_body<MODE_QKV>(smem, smem + 8192, (bid / 24) * 128, (bid % 24) * 128,
                            xb, WqkvT, 1024, 3072, bq, bk, bv, nullptr,
                            out_pt, nullptr, qbuf, Kbf, Vtbf, kvidx);
        return;
    }
    if (bid < 864) {
        // ---- K-prep: 64 tokens (4 pages) x all heads; fully sequential reads ----
        int kb2 = bid - 384;           // 0..479
        int tile = kb2 % 60, b = kb2 / 60;
        int T0 = tile * 64;
        int h = tid >> 4, hd0 = (tid & 15) * 4;   // col c = tid*4
#pragma unroll
        for (int pi = 0; pi < 4; ++pi) {
            int page = kvidx[b * 256 + (T0 >> 4) + pi];
            const float* src = pgt + (size_t)page * 32768;
            float* dst = out_pt + (size_t)page * 32768;
            size_t kdst = ((size_t)(b * 16 + h) * 4096 + T0 + pi * 16) * 64 + hd0;
#pragma unroll
            for (int it = 0; it < 16; ++it) {
                size_t o = (size_t)it * 1024 + tid * 4;
                float4 f = *(const float4*)(src + o);
                *(float4*)(dst + o) = f;
                u16 k4[4] = {f2bf(f.x), f2bf(f.y), f2bf(f.z), f2bf(f.w)};
                *(uint2*)&Kbf[kdst + (size_t)it * 64] = *(const uint2*)k4;
            }
        }
        return;
    }
    // ---- V-prep: 64 tokens (4 pages) x all heads, via LDS transpose in 4 chunks ----
    int vb2 = bid - 864;               // 0..479
    int tile = vb2 % 60, b = vb2 / 60;
    int T0 = tile * 64;
    int pg[4];
#pragma unroll
    for (int pi = 0; pi < 4; ++pi) pg[pi] = kvidx[b * 256 + (T0 >> 4) + pi];
    u16* vt = smem;                    // [64][260]
    int g = tid >> 4, j = tid & 15;    // write-phase roles
    for (int hb = 0; hb < 4; ++hb) {
#pragma unroll
        for (int it = 0; it < 16; ++it) {
            int pi = it >> 2;
            int tokloc = (it & 3) * 4 + (tid >> 6);   // 0..15 within page
            int ti = pi * 16 + tokloc;                // 0..63 within tile
            int c4 = tid & 63;
            size_t o = (size_t)pg[pi] * 32768 + 16384 + (size_t)tokloc * 1024
                       + hb * 256 + c4 * 4;
            float4 v = *(const float4*)(pgt + o);
            *(float4*)(out_pt + o) = v;
            u16 v4[4] = {f2bf(v.x), f2bf(v.y), f2bf(v.z), f2bf(v.w)};
            *(uint2*)&vt[ti * 260 + c4 * 4] = *(const uint2*)v4;
        }
        __syncthreads();
#pragma unroll
        for (int rp = 0; rp < 16; ++rp) {
            int ri = rp * 16 + g;                     // chunk-local col 0..255
            int h = hb * 4 + (ri >> 6), hd = ri & 63;
            u16 o4[4];
#pragma unroll
            for (int s = 0; s < 4; ++s) o4[s] = vt[(j * 4 + s) * 260 + ri];
            *(uint2*)&Vtbf[((size_t)(b * 16 + h) * 64 + hd) * 4096 + T0 + j * 4] =
                *(const uint2*)o4;
        }
        __syncthreads();
    }
}

// ---------------- attention (1024 blocks) + Wo/W1/W2 transposes (4608 blocks x2) ----
__global__ __launch_bounds__(512) void attn_kernel(const u16* __restrict__ qb,
                                                   const u16* __restrict__ Kbf,
                                                   const u16* __restrict__ Vtbf,
                                                   float* __restrict__ pOct,
                                                   float* __restrict__ pL,
                                                   const float* __restrict__ Wo,
                                                   const float* __restrict__ W1,
                                                   const float* __restrict__ W2,
                                                   u16* __restrict__ WoT,
                                                   u16* __restrict__ W1T,
                                                   u16* __restrict__ W2T) {
    __shared__ u16 Ks[64 * 64];
    __shared__ u16 Vt[64 * 64];
    __shared__ u16 Ps[8][16 * 64];
    int bid = blockIdx.x;
    int tid = threadIdx.x;
    if (bid >= 1024) {
        // ---- weight transposes: 2 x 32x32 tiles per block (512 threads) ----
        int sub = tid >> 8, t2 = tid & 255;
        int wb = (bid - 1024) * 2 + sub;   // 0..9215
        const float* src; u16* dst; int K, N, bx, by;
        if (wb < 1024) {
            bx = wb & 31; by = wb >> 5; K = 1024; N = 1024; src = Wo; dst = WoT;
        } else if (wb < 5120) {
            int r = wb - 1024; bx = r & 127; by = r >> 7; K = 1024; N = 4096; src = W1; dst = W1T;
        } else {
            int r = wb - 5120; bx = r & 31; by = r >> 5; K = 4096; N = 1024; src = W2; dst = W2T;
        }
        float* t = sub ? (float*)Vt : (float*)Ks;   // each 8KB >= 4224B
        int tx = t2 & 31, ty = t2 >> 5;
        int n0 = bx * 32, k0 = by * 32;
#pragma unroll
        for (int jj = 0; jj < 32; jj += 8)
            t[(ty + jj) * 33 + tx] = src[(size_t)(k0 + ty + jj) * N + n0 + tx];
        __syncthreads();
#pragma unroll
        for (int jj = 0; jj < 32; jj += 8)
            dst[(size_t)(n0 + ty + jj) * K + k0 + tx] = f2bf(t[tx * 33 + ty + jj]);
        return;
    }
    int l = tid & 63, w = tid >> 6;
    int lr = l & 15, lg = l >> 4;
    int x = bid & 7, qt = x >> 2, split = x & 3;
    int h = (bid >> 3) & 15, b = bid >> 7;

    int qrow = qt * 128 + w * 16 + lr;
    const u16* qptr = qb + (size_t)(b * 256 + qrow) * 1024 + h * 64 + lg * 8;
    short8 qf0 = *(const short8*)qptr;
    short8 qf1 = *(const short8*)(qptr + 32);

    const u16* kslab = Kbf + (size_t)(b * 16 + h) * 4096 * 64;
    const u16* vslab = Vtbf + (size_t)(b * 16 + h) * 64 * 4096;

    f32x4 octx[4] = {};
    f32x4 lacc = {};
    short8 ones;
#pragma unroll
    for (int jj = 0; jj < 8; jj++) ones[jj] = (short)0x3F80;

    int qbase = 3840 + qt * 128;
    int ntiles = (qbase + 128) >> 6;
    int tstart = split * 16;
    int tend = min(tstart + 16, ntiles);
    int kt0 = tstart * 64, kt1 = tend * 64;

    int srow = tid >> 3, scol8 = (tid & 7) * 8;
    int sdst = srow * 64 + (scol8 ^ ((srow & 7) << 3));
    const u16* kp = kslab + srow * 64 + scol8;
    const u16* vp = vslab + (size_t)srow * 4096 + scol8;

    uint4 kreg = *(const uint4*)(kp + (size_t)kt0 * 64);
    uint4 vreg = *(const uint4*)(vp + kt0);
    for (int kt = kt0; kt < kt1; kt += 64) {
        *(uint4*)&Ks[sdst] = kreg;
        *(uint4*)&Vt[sdst] = vreg;
        __syncthreads();
        bool hn = (kt + 64) < kt1;
        if (hn) {
            kreg = *(const uint4*)(kp + (size_t)(kt + 64) * 64);
            vreg = *(const uint4*)(vp + kt + 64);
        }
        float P[4][4];
        bool need_mask = (kt + 63 > qbase);
#pragma unroll
        for (int ni = 0; ni < 4; ni++) {
            f32x4 s = {};
            int krow = ni * 16 + lr;
            int swz = (krow & 7) << 3;
            short8 k0 = *(const short8*)&Ks[krow * 64 + ((lg * 8) ^ swz)];
            short8 k1 = *(const short8*)&Ks[krow * 64 + ((32 + lg * 8) ^ swz)];
            s = __builtin_amdgcn_mfma_f32_16x16x32_bf16(qf0, k0, s, 0, 0, 0);
            s = __builtin_amdgcn_mfma_f32_16x16x32_bf16(qf1, k1, s, 0, 0, 0);
            if (need_mask) {
                int col = kt + ni * 16 + lr;
#pragma unroll
                for (int r = 0; r < 4; r++) {
                    int q = qt * 128 + w * 16 + lg * 4 + r;
                    P[ni][r] = (col <= 3840 + q) ? __expf(s[r]) : 0.0f;
                }
            } else {
#pragma unroll
                for (int r = 0; r < 4; r++) P[ni][r] = __expf(s[r]);
            }
        }
#pragma unroll
        for (int ni = 0; ni < 4; ni++)
#pragma unroll
            for (int r = 0; r < 4; r++) {
                int prow = lg * 4 + r;
                Ps[w][prow * 64 + ((ni * 16 + lr) ^ ((prow & 7) << 3))] = f2bf(P[ni][r]);
            }
#pragma unroll
        for (int kk = 0; kk < 2; kk++) {
            int c0 = kk * 32 + lg * 8;
            short8 pf = *(const short8*)&Ps[w][lr * 64 + (c0 ^ ((lr & 7) << 3))];
            lacc = __builtin_amdgcn_mfma_f32_16x16x32_bf16(pf, ones, lacc, 0, 0, 0);
#pragma unroll
            for (int dt = 0; dt < 4; dt++) {
                int vrow = dt * 16 + lr;
                short8 vf = *(const short8*)&Vt[vrow * 64 + (c0 ^ ((vrow & 7) << 3))];
                octx[dt] = __builtin_amdgcn_mfma_f32_16x16x32_bf16(pf, vf, octx[dt], 0, 0, 0);
            }
        }
        __syncthreads();
    }
    size_t obase = (((size_t)(split * 8 + b) * 16 + h) * 256 + qt * 128) * 64;
#pragma unroll
    for (int dt = 0; dt < 4; dt++)
#pragma unroll
        for (int r = 0; r < 4; r++)
            pOct[obase + (size_t)(w * 16 + lg * 4 + r) * 64 + dt * 16 + lr] = octx[dt][r];
    if (lr == 0) {
        size_t lbase = ((size_t)(split * 8 + b) * 16 + h) * 256 + qt * 128;
#pragma unroll
        for (int r = 0; r < 4; r++) pL[lbase + w * 16 + lg * 4 + r] = lacc[r];
    }
}

// ---------------- combine partials -> ctx bf16 ----------------
__global__ __launch_bounds__(256) void attn_combine(const float* __restrict__ pOct,
                                                    const float* __restrict__ pL,
                                                    u16* __restrict__ ctxb) {
    int row = blockIdx.x;
    int b = row >> 8, q = row & 255;
    int tid = threadIdx.x;
    int h = tid >> 4, dq = (tid & 15) * 4;
    size_t stride = (size_t)128 * 256 * 64;
    size_t base = ((size_t)(b * 16 + h) * 256 + q) * 64 + dq;
    size_t lstride = 128 * 256;
    size_t lbase = (size_t)(b * 16 + h) * 256 + q;
    f32x4 s = {};
    float ls = 0.0f;
#pragma unroll
    for (int sp = 0; sp < 4; sp++) {
        f32x4 v = *(const f32x4*)(pOct + sp * stride + base);
        s += v;
        ls += pL[sp * lstride + lbase];
    }
    float inv = 1.0f / ls;
    u16 o[4] = {f2bf(s[0] * inv), f2bf(s[1] * inv), f2bf(s[2] * inv), f2bf(s[3] * inv)};
    *(uint2*)&ctxb[(size_t)row * 1024 + h * 64 + dq] = *(const uint2*)o;
}

// ---------------- launch ----------------
extern "C" void kernel_launch(void* const* d_in, const int* in_sizes, int n_in,
                              void* d_out, int out_size, void* d_ws, size_t ws_size,
                              hipStream_t stream) {
    (void)in_sizes; (void)n_in; (void)out_size; (void)ws_size;
    const float* x   = (const float*)d_in[0];
    const float* pgt = (const float*)d_in[1];
    const float* Wq  = (const float*)d_in[2];
    const float* bq  = (const float*)d_in[3];
    const float* Wk  = (const float*)d_in[4];
    const float* bk  = (const float*)d_in[5];
    const float* Wv  = (const float*)d_in[6];
    const float* bv  = (const float*)d_in[7];
    const float* Wo  = (const float*)d_in[8];
    const float* bo  = (const float*)d_in[9];
    const float* ln1g = (const float*)d_in[10];
    const float* ln1b = (const float*)d_in[11];
    const float* W1  = (const float*)d_in[12];
    const float* b1  = (const float*)d_in[13];
    const float* W2  = (const float*)d_in[14];
    const float* b2  = (const float*)d_in[15];
    const float* lnfg = (const float*)d_in[16];
    const float* lnfb = (const float*)d_in[17];
    const int* kvidx = (const int*)d_in[20];

    float* out = (float*)d_out;
    float* out_x  = out;
    float* out_lr = out + 2048 * 1024;
    float* out_pt = out + 2 * 2048 * 1024;

    char* ws = (char*)d_ws;
    size_t off = 0;
    auto alloc = [&](size_t bytes) { void* p = ws + off; off += (bytes + 255) & ~(size_t)255; return p; };
    u16* WqkvT = (u16*)alloc((size_t)3072 * 1024 * 2);
    u16* WoT   = (u16*)alloc((size_t)1024 * 1024 * 2);
    u16* W1T   = (u16*)alloc((size_t)4096 * 1024 * 2);
    u16* W2T   = (u16*)alloc((size_t)1024 * 4096 * 2);
    u16* xb    = (u16*)alloc((size_t)2048 * 1024 * 2);
    u16* qbuf  = (u16*)alloc((size_t)2048 * 1024 * 2);
    u16* ctxb  = (u16*)alloc((size_t)2048 * 1024 * 2);
    char* regB = (char*)alloc((size_t)2 * 8 * 16 * 4096 * 64 * 2);
    u16* Kbf  = (u16*)regB;
    u16* Vtbf = (u16*)(regB + (size_t)64 * 1024 * 1024);
    float* pOct = (float*)(regB + (size_t)128 * 1024 * 1024);
    float* pL   = (float*)(regB + (size_t)162 * 1024 * 1024);
    float* t1    = (float*)regB;
    float* xln1f = (float*)(regB + (size_t)8 * 1024 * 1024);
    u16*   hb    = (u16*)(regB + (size_t)16 * 1024 * 1024);
    u16*   xln1b = (u16*)(regB + (size_t)32 * 1024 * 1024);
    float* t2 = t1;

    prep_wx<<<4096, 256, 0, stream>>>(Wq, Wk, Wv, x, WqkvT, xb);
    mega_prep<<<1344, 256, 0, stream>>>(xb, WqkvT, bq, bk, bv,
                                        out_pt, qbuf, Kbf, Vtbf, pgt, kvidx);
    attn_kernel<<<5632, 512, 0, stream>>>(qbuf, Kbf, Vtbf, pOct, pL,
                                          Wo, W1, W2, WoT, W1T, W2T);
    attn_combine<<<2048, 256, 0, stream>>>(pOct, pL, ctxb);
    gemm_nt<MODE_WO><<<128, 256, 0, stream>>>(ctxb, WoT, 1024, 1024, 8,
        bo, x, t1, nullptr, nullptr);
    ln_row<<<2048, 256, 0, stream>>>(t1, ln1g, ln1b, xln1f, xln1b);
    gemm_nt<MODE_F1><<<512, 256, 0, stream>>>(xln1b, W1T, 1024, 4096, 32,
        b1, nullptr, nullptr, nullptr, hb);
    gemm_nt<MODE_F2><<<128, 256, 0, stream>>>(hb, W2T, 4096, 1024, 8,
        b2, xln1f, out_lr, t2, nullptr);
    ln_row<<<2048, 256, 0, stream>>>(t2, lnfg, lnfb, out_x, nullptr);
}

// Round 11
// 338.530 us; speedup vs baseline: 1.2992x; 1.1233x over previous
//
#include <hip/hip_runtime.h>
#include <hip/hip_bf16.h>

typedef unsigned short u16;
typedef __attribute__((ext_vector_type(4))) float f32x4;
typedef __attribute__((ext_vector_type(8))) short short8;

// B=8 QLEN=256 D=1024 H=16 HD=64 FFN=4096 PAGE=16 KV_TOTAL=4096 P=256
// PREFIX=3840 SCALE=0.125
#define MODE_QKV 0
#define MODE_WO  1
#define MODE_F1  2
#define MODE_F2  3

__device__ inline u16 f2bf(float f) {
    __hip_bfloat16 h = __float2bfloat16(f);
    return *(u16*)&h;
}

typedef __attribute__((address_space(3))) unsigned int lds_u32_t;
typedef const __attribute__((address_space(1))) unsigned int glb_u32_t;
__device__ inline void gload16(const u16* g, u16* l) {
    __builtin_amdgcn_global_load_lds((glb_u32_t*)(const void*)g,
                                     (lds_u32_t*)(void*)l, 16, 0, 0);
}

// ---------------- prep: Wq/Wk/Wv transposes + x cast ----------------
__global__ __launch_bounds__(256) void prep_wx(
    const float* __restrict__ Wq, const float* __restrict__ Wk,
    const float* __restrict__ Wv, const float* __restrict__ x,
    u16* __restrict__ WqkvT, u16* __restrict__ xb) {
    int bid = blockIdx.x;
    int tid = threadIdx.x;
    int tx = tid & 31, ty = tid >> 5;
    if (bid >= 3072) {
        int i = (bid - 3072) * 256 + tid;
        const float4* p = (const float4*)(x + (size_t)i * 8);
        float4 a = p[0], b = p[1];
        u16 t[8] = {f2bf(a.x), f2bf(a.y), f2bf(a.z), f2bf(a.w),
                    f2bf(b.x), f2bf(b.y), f2bf(b.z), f2bf(b.w)};
        *(uint4*)(xb + (size_t)i * 8) = *(const uint4*)t;
        return;
    }
    int m = bid >> 10, r = bid & 1023;
    const float* src = (m == 0) ? Wq : (m == 1) ? Wk : Wv;
    u16* dst = WqkvT + (size_t)m * 1024 * 1024;
    __shared__ float t[32][33];
    int n0 = (r & 31) * 32, k0 = (r >> 5) * 32;
#pragma unroll
    for (int j = 0; j < 32; j += 8)
        t[ty + j][tx] = src[(size_t)(k0 + ty + j) * 1024 + n0 + tx];
    __syncthreads();
#pragma unroll
    for (int j = 0; j < 32; j += 8)
        dst[(size_t)(n0 + ty + j) * 1024 + k0 + tx] = f2bf(t[tx][ty + j]);
}

// ---------------- LN after WO: t = p0+p1+bo+resid; LN -> xln1f, xln1b ------------
__global__ __launch_bounds__(256) void ln_wo(const float* __restrict__ p0,
                                             const float* __restrict__ p1,
                                             const float* __restrict__ bo,
                                             const float* __restrict__ resid,
                                             const float* __restrict__ g,
                                             const float* __restrict__ be,
                                             float* __restrict__ outf,
                                             u16* __restrict__ outb) {
    int row = blockIdx.x;
    int tid = threadIdx.x;
    int c = tid * 4;
    size_t o = (size_t)row * 1024 + c;
    f32x4 v = *(const f32x4*)(p0 + o) + *(const f32x4*)(p1 + o)
            + *(const f32x4*)(bo + c) + *(const f32x4*)(resid + o);
    float s = v[0] + v[1] + v[2] + v[3];
#pragma unroll
    for (int m = 1; m < 64; m <<= 1) s += __shfl_xor(s, m, 64);
    __shared__ float red1[4], red2[4];
    int w = tid >> 6;
    if ((tid & 63) == 0) red1[w] = s;
    __syncthreads();
    float mu = (red1[0] + red1[1] + red1[2] + red1[3]) * (1.0f / 1024.0f);
    f32x4 d = v - mu;
    float q = d[0] * d[0] + d[1] * d[1] + d[2] * d[2] + d[3] * d[3];
#pragma unroll
    for (int m = 1; m < 64; m <<= 1) q += __shfl_xor(q, m, 64);
    if ((tid & 63) == 0) red2[w] = q;
    __syncthreads();
    float var = (red2[0] + red2[1] + red2[2] + red2[3]) * (1.0f / 1024.0f);
    float rs = rsqrtf(var + 1e-5f);
    f32x4 gg = *(const f32x4*)(g + c), bb = *(const f32x4*)(be + c);
    f32x4 ov = d * rs * gg + bb;
    *(f32x4*)(outf + o) = ov;
    u16 t[4] = {f2bf(ov[0]), f2bf(ov[1]), f2bf(ov[2]), f2bf(ov[3])};
    *(uint2*)&outb[o] = *(const uint2*)t;
}

// ------- final LN: lr = q0+q1+q2+q3+b2 -> out_lr; LN(lr + xln1f) -> out_x --------
__global__ __launch_bounds__(256) void ln_f2(const float* __restrict__ q0,
                                             const float* __restrict__ b2,
                                             const float* __restrict__ xln1f,
                                             const float* __restrict__ g,
                                             const float* __restrict__ be,
                                             float* __restrict__ out_lr,
                                             float* __restrict__ out_x) {
    int row = blockIdx.x;
    int tid = threadIdx.x;
    int c = tid * 4;
    size_t o = (size_t)row * 1024 + c;
    const size_t st = (size_t)2048 * 1024;
    f32x4 v = *(const f32x4*)(q0 + o) + *(const f32x4*)(q0 + st + o)
            + *(const f32x4*)(q0 + 2 * st + o) + *(const f32x4*)(q0 + 3 * st + o)
            + *(const f32x4*)(b2 + c);
    *(f32x4*)(out_lr + o) = v;
    v = v + *(const f32x4*)(xln1f + o);
    float s = v[0] + v[1] + v[2] + v[3];
#pragma unroll
    for (int m = 1; m < 64; m <<= 1) s += __shfl_xor(s, m, 64);
    __shared__ float red1[4], red2[4];
    int w = tid >> 6;
    if ((tid & 63) == 0) red1[w] = s;
    __syncthreads();
    float mu = (red1[0] + red1[1] + red1[2] + red1[3]) * (1.0f / 1024.0f);
    f32x4 d = v - mu;
    float q = d[0] * d[0] + d[1] * d[1] + d[2] * d[2] + d[3] * d[3];
#pragma unroll
    for (int m = 1; m < 64; m <<= 1) q += __shfl_xor(q, m, 64);
    if ((tid & 63) == 0) red2[w] = q;
    __syncthreads();
    float var = (red2[0] + red2[1] + red2[2] + red2[3]) * (1.0f / 1024.0f);
    float rs = rsqrtf(var + 1e-5f);
    f32x4 gg = *(const f32x4*)(g + c), bb = *(const f32x4*)(be + c);
    *(f32x4*)(out_x + o) = d * rs * gg + bb;
}

// ---------------- GEMM body: tile 128x128, BK=64, row stride lda ----------------
template <int MODE>
__device__ __forceinline__ void gemm_body(
    u16* As, u16* Bs, int m0, int n0,
    const u16* __restrict__ A, const u16* __restrict__ Bt, int lda, int Kspan, int N,
    const float* __restrict__ bias0, const float* __restrict__ bias1,
    const float* __restrict__ bias2,
    float* __restrict__ o0, u16* __restrict__ ob,
    u16* __restrict__ kbf, u16* __restrict__ vbf, const int* __restrict__ kvidx) {
    int tid = threadIdx.x;
    int l = tid & 63, w = tid >> 6;
    int wr = w >> 1, wc = w & 1;
    int lr = l & 15, lg = l >> 4;
    int lrow8 = l >> 3;
    int scol = ((l & 7) ^ lrow8) << 3;
    f32x4 acc[4][4] = {};
    for (int kb = 0; kb < Kspan; kb += 64) {
#pragma unroll
        for (int p = 0; p < 4; ++p) {
            int chunk = p * 4 + w;
            int r = chunk * 8 + lrow8;
            gload16(&A[(size_t)(m0 + r) * lda + kb + scol], &As[chunk * 512]);
            gload16(&Bt[(size_t)(n0 + r) * lda + kb + scol], &Bs[chunk * 512]);
        }
        __syncthreads();
#pragma unroll
        for (int kk = 0; kk < 2; ++kk) {
            short8 a[4], b[4];
            int c0 = kk * 32 + lg * 8;
#pragma unroll
            for (int mi = 0; mi < 4; mi++) {
                int row = wr * 64 + mi * 16 + lr;
                a[mi] = *(const short8*)&As[row * 64 + (c0 ^ ((row & 7) << 3))];
            }
#pragma unroll
            for (int ni = 0; ni < 4; ni++) {
                int row = wc * 64 + ni * 16 + lr;
                b[ni] = *(const short8*)&Bs[row * 64 + (c0 ^ ((row & 7) << 3))];
            }
#pragma unroll
            for (int mi = 0; mi < 4; mi++)
#pragma unroll
                for (int ni = 0; ni < 4; ni++)
                    acc[mi][ni] = __builtin_amdgcn_mfma_f32_16x16x32_bf16(
                        a[mi], b[ni], acc[mi][ni], 0, 0, 0);
        }
        __syncthreads();
    }
#pragma unroll
    for (int mi = 0; mi < 4; mi++) {
#pragma unroll
        for (int ni = 0; ni < 4; ni++) {
#pragma unroll
            for (int r = 0; r < 4; r++) {
                int row = m0 + wr * 64 + mi * 16 + lg * 4 + r;
                int col = n0 + wc * 64 + ni * 16 + lr;
                float v = acc[mi][ni][r];
                if constexpr (MODE == MODE_QKV) {
                    int sel = col >> 10, c = col & 1023;
                    int b = row >> 8, ii = row & 255;
                    int h = (c >> 6), hd = c & 63;
                    if (sel == 0) {
                        ob[(size_t)row * 1024 + c] = f2bf((v + bias0[c]) * 0.125f);
                    } else if (sel == 1) {
                        float val = v + bias1[c];
                        int page = kvidx[b * 256 + 240 + (ii >> 4)];
                        o0[(size_t)page * 32768 + (size_t)(ii & 15) * 1024 + c] = val;
                        kbf[((size_t)(b * 16 + h) * 4096 + 3840 + ii) * 64 + hd] = f2bf(val);
                    } else {
                        float val = v + bias2[c];
                        int page = kvidx[b * 256 + 240 + (ii >> 4)];
                        o0[(size_t)page * 32768 + 16384 + (size_t)(ii & 15) * 1024 + c] = val;
                        vbf[((size_t)(b * 16 + h) * 64 + hd) * 4096 + 3840 + ii] = f2bf(val);
                    }
                } else if constexpr (MODE == MODE_F1) {
                    float t = v + bias0[col];
                    ob[(size_t)row * N + col] = f2bf(fmaxf(t, 0.0f));
                } else { // WO / F2: raw split-K partial
                    o0[(size_t)row * N + col] = v;
                }
            }
        }
    }
}

// split-K wrapper: split = bid / nper; o0 += split*osplit; A/Bt += split*Kspan
template <int MODE>
__global__ __launch_bounds__(256) void gemm_nt(
    const u16* __restrict__ A, const u16* __restrict__ Bt,
    int lda, int Kspan, int N, int gx, int nper,
    const float* __restrict__ bias0,
    float* __restrict__ o0, u16* __restrict__ ob, size_t osplit) {
    __shared__ __align__(16) u16 smem[128 * 64 * 2];
    int bid = blockIdx.x;
    int split = bid / nper, t = bid % nper;
    gemm_body<MODE>(smem, smem + 128 * 64, (t / gx) * 128, (t % gx) * 128,
                    A + (size_t)split * Kspan, Bt + (size_t)split * Kspan,
                    lda, Kspan, N, bias0, nullptr, nullptr,
                    o0 ? o0 + (size_t)split * osplit : nullptr, ob,
                    nullptr, nullptr, nullptr);
}

// ---- mega: K-prep [0,480) + V-prep [480,960) + QKV GEMM [960,1344) + transposes ----
__global__ __launch_bounds__(256) void mega_prep(
    const u16* __restrict__ xb, const u16* __restrict__ WqkvT,
    const float* __restrict__ bq, const float* __restrict__ bk,
    const float* __restrict__ bv,
    float* __restrict__ out_pt, u16* __restrict__ qbuf,
    u16* __restrict__ Kbf, u16* __restrict__ Vtbf,
    const float* __restrict__ pgt, const int* __restrict__ kvidx,
    const float* __restrict__ Wo, const float* __restrict__ W1,
    const float* __restrict__ W2,
    u16* __restrict__ WoT, u16* __restrict__ W1T, u16* __restrict__ W2T) {
    __shared__ __align__(16) u16 smem[128 * 64 * 2]; // 32KB shared by all branches
    int bid = blockIdx.x;
    int tid = threadIdx.x;
    if (bid < 480) {
        // ---- K-prep: 64 tokens x all heads; sequential page reads; f32 copy + bf16 ----
        int tile = bid % 60, b = bid / 60;
        int T0 = tile * 64;
        int h = tid >> 4, hd0 = (tid & 15) * 4;
        int pg[4];
#pragma unroll
        for (int pi = 0; pi < 4; ++pi) pg[pi] = kvidx[b * 256 + (T0 >> 4) + pi];
#pragma unroll 4
        for (int it2 = 0; it2 < 64; ++it2) {
            int pi = it2 >> 4, it = it2 & 15;
            const float* src = pgt + (size_t)pg[pi] * 32768;
            float* dst = out_pt + (size_t)pg[pi] * 32768;
            size_t o = (size_t)it * 1024 + tid * 4;
            float4 f = *(const float4*)(src + o);
            *(float4*)(dst + o) = f;
            u16 k4[4] = {f2bf(f.x), f2bf(f.y), f2bf(f.z), f2bf(f.w)};
            size_t kdst = ((size_t)(b * 16 + h) * 4096 + T0 + pi * 16 + it) * 64 + hd0;
            *(uint2*)&Kbf[kdst] = *(const uint2*)k4;
        }
        return;
    }
    if (bid < 960) {
        // ---- V-prep: 64 tokens x 2 heads per chunk (8 chunks), LDS transpose ----
        int vb2 = bid - 480;
        int tile = vb2 % 60, b = vb2 / 60;
        int T0 = tile * 64;
        int pg[4];
#pragma unroll
        for (int pi = 0; pi < 4; ++pi) pg[pi] = kvidx[b * 256 + (T0 >> 4) + pi];
        u16* vt = smem; // [64][134]
        for (int hb2 = 0; hb2 < 8; ++hb2) {
#pragma unroll 4
            for (int it = 0; it < 8; ++it) {
                int ti = it * 8 + (tid >> 5);
                int pi = ti >> 4, tokloc = ti & 15;
                int c4 = (tid & 31) * 4;
                size_t o = (size_t)pg[pi] * 32768 + 16384 + (size_t)tokloc * 1024
                           + hb2 * 128 + c4;
                float4 v = *(const float4*)(pgt + o);
                *(float4*)(out_pt + o) = v;
                u16 v4[4] = {f2bf(v.x), f2bf(v.y), f2bf(v.z), f2bf(v.w)};
                *(uint2*)&vt[ti * 134 + c4] = *(const uint2*)v4;
            }
            __syncthreads();
            int g = tid >> 4, j = tid & 15;
#pragma unroll
            for (int rp = 0; rp < 8; ++rp) {
                int ri = rp * 16 + g;              // 0..127 chunk-local col
                int h = hb2 * 2 + (ri >> 6), hd = ri & 63;
                u16 o4[4];
#pragma unroll
                for (int s = 0; s < 4; ++s) o4[s] = vt[(j * 4 + s) * 134 + ri];
                *(uint2*)&Vtbf[((size_t)(b * 16 + h) * 64 + hd) * 4096 + T0 + j * 4] =
                    *(const uint2*)o4;
            }
            __syncthreads();
        }
        return;
    }
    if (bid < 1344) {
        int t = bid - 960;
        gemm_body<MODE_QKV>(smem, smem + 8192, (t / 24) * 128, (t % 24) * 128,
                            xb, WqkvT, 1024, 1024, 3072, bq, bk, bv,
                            out_pt, qbuf, Kbf, Vtbf, kvidx);
        return;
    }
    // ---- Wo/W1/W2 transposes ----
    int wb = bid - 1344;
    const float* src; u16* dst; int K, N, bx, by;
    if (wb < 1024) {
        bx = wb & 31; by = wb >> 5; K = 1024; N = 1024; src = Wo; dst = WoT;
    } else if (wb < 5120) {
        int r = wb - 1024; bx = r & 127; by = r >> 7; K = 1024; N = 4096; src = W1; dst = W1T;
    } else {
        int r = wb - 5120; bx = r & 31; by = r >> 5; K = 4096; N = 1024; src = W2; dst = W2T;
    }
    float* t = (float*)smem; // [32][33]
    int tx = tid & 31, ty = tid >> 5;
    int n0 = bx * 32, k0 = by * 32;
#pragma unroll
    for (int j = 0; j < 32; j += 8)
        t[(ty + j) * 33 + tx] = src[(size_t)(k0 + ty + j) * N + n0 + tx];
    __syncthreads();
#pragma unroll
    for (int j = 0; j < 32; j += 8)
        dst[(size_t)(n0 + ty + j) * K + k0 + tx] = f2bf(t[tx * 33 + ty + j]);
}

// ---------------- attention: single-buffer + reg prefetch, KV-split x4 ----------------
__global__ __launch_bounds__(512) void attn_kernel(const u16* __restrict__ qb,
                                                   const u16* __restrict__ Kbf,
                                                   const u16* __restrict__ Vtbf,
                                                   float* __restrict__ pOct,
                                                   float* __restrict__ pL) {
    __shared__ u16 Ks[64 * 64];
    __shared__ u16 Vt[64 * 64];
    __shared__ u16 Ps[8][16 * 64];
    int bid = blockIdx.x;
    int tid = threadIdx.x;
    int l = tid & 63, w = tid >> 6;
    int lr = l & 15, lg = l >> 4;
    int x = bid & 7, qt = x >> 2, split = x & 3;
    int h = (bid >> 3) & 15, b = bid >> 7;

    int qrow = qt * 128 + w * 16 + lr;
    const u16* qptr = qb + (size_t)(b * 256 + qrow) * 1024 + h * 64 + lg * 8;
    short8 qf0 = *(const short8*)qptr;
    short8 qf1 = *(const short8*)(qptr + 32);

    const u16* kslab = Kbf + (size_t)(b * 16 + h) * 4096 * 64;
    const u16* vslab = Vtbf + (size_t)(b * 16 + h) * 64 * 4096;

    f32x4 octx[4] = {};
    f32x4 lacc = {};
    short8 ones;
#pragma unroll
    for (int jj = 0; jj < 8; jj++) ones[jj] = (short)0x3F80;

    int qbase = 3840 + qt * 128;
    int ntiles = (qbase + 128) >> 6;
    int tstart = split * 16;
    int tend = min(tstart + 16, ntiles);
    int kt0 = tstart * 64, kt1 = tend * 64;

    int srow = tid >> 3, scol8 = (tid & 7) * 8;
    int sdst = srow * 64 + (scol8 ^ ((srow & 7) << 3));
    const u16* kp = kslab + srow * 64 + scol8;
    const u16* vp = vslab + (size_t)srow * 4096 + scol8;

    uint4 kreg = *(const uint4*)(kp + (size_t)kt0 * 64);
    uint4 vreg = *(const uint4*)(vp + kt0);
    for (int kt = kt0; kt < kt1; kt += 64) {
        *(uint4*)&Ks[sdst] = kreg;
        *(uint4*)&Vt[sdst] = vreg;
        __syncthreads();
        bool hn = (kt + 64) < kt1;
        if (hn) {
            kreg = *(const uint4*)(kp + (size_t)(kt + 64) * 64);
            vreg = *(const uint4*)(vp + kt + 64);
        }
        float P[4][4];
        bool need_mask = (kt + 63 > qbase);
#pragma unroll
        for (int ni = 0; ni < 4; ni++) {
            f32x4 s = {};
            int krow = ni * 16 + lr;
            int swz = (krow & 7) << 3;
            short8 k0 = *(const short8*)&Ks[krow * 64 + ((lg * 8) ^ swz)];
            short8 k1 = *(const short8*)&Ks[krow * 64 + ((32 + lg * 8) ^ swz)];
            s = __builtin_amdgcn_mfma_f32_16x16x32_bf16(qf0, k0, s, 0, 0, 0);
            s = __builtin_amdgcn_mfma_f32_16x16x32_bf16(qf1, k1, s, 0, 0, 0);
            if (need_mask) {
                int col = kt + ni * 16 + lr;
#pragma unroll
                for (int r = 0; r < 4; r++) {
                    int q = qt * 128 + w * 16 + lg * 4 + r;
                    P[ni][r] = (col <= 3840 + q) ? __expf(s[r]) : 0.0f;
                }
            } else {
#pragma unroll
                for (int r = 0; r < 4; r++) P[ni][r] = __expf(s[r]);
            }
        }
#pragma unroll
        for (int ni = 0; ni < 4; ni++)
#pragma unroll
            for (int r = 0; r < 4; r++) {
                int prow = lg * 4 + r;
                Ps[w][prow * 64 + ((ni * 16 + lr) ^ ((prow & 7) << 3))] = f2bf(P[ni][r]);
            }
#pragma unroll
        for (int kk = 0; kk < 2; kk++) {
            int c0 = kk * 32 + lg * 8;
            short8 pf = *(const short8*)&Ps[w][lr * 64 + (c0 ^ ((lr & 7) << 3))];
            lacc = __builtin_amdgcn_mfma_f32_16x16x32_bf16(pf, ones, lacc, 0, 0, 0);
#pragma unroll
            for (int dt = 0; dt < 4; dt++) {
                int vrow = dt * 16 + lr;
                short8 vf = *(const short8*)&Vt[vrow * 64 + (c0 ^ ((vrow & 7) << 3))];
                octx[dt] = __builtin_amdgcn_mfma_f32_16x16x32_bf16(pf, vf, octx[dt], 0, 0, 0);
            }
        }
        __syncthreads();
    }
    size_t obase = (((size_t)(split * 8 + b) * 16 + h) * 256 + qt * 128) * 64;
#pragma unroll
    for (int dt = 0; dt < 4; dt++)
#pragma unroll
        for (int r = 0; r < 4; r++)
            pOct[obase + (size_t)(w * 16 + lg * 4 + r) * 64 + dt * 16 + lr] = octx[dt][r];
    if (lr == 0) {
        size_t lbase = ((size_t)(split * 8 + b) * 16 + h) * 256 + qt * 128;
#pragma unroll
        for (int r = 0; r < 4; r++) pL[lbase + w * 16 + lg * 4 + r] = lacc[r];
    }
}

// ---------------- combine partials -> ctx bf16 ----------------
__global__ __launch_bounds__(256) void attn_combine(const float* __restrict__ pOct,
                                                    const float* __restrict__ pL,
                                                    u16* __restrict__ ctxb) {
    int row = blockIdx.x;
    int b = row >> 8, q = row & 255;
    int tid = threadIdx.x;
    int h = tid >> 4, dq = (tid & 15) * 4;
    size_t stride = (size_t)128 * 256 * 64;
    size_t base = ((size_t)(b * 16 + h) * 256 + q) * 64 + dq;
    size_t lstride = 128 * 256;
    size_t lbase = (size_t)(b * 16 + h) * 256 + q;
    f32x4 s = {};
    float ls = 0.0f;
#pragma unroll
    for (int sp = 0; sp < 4; sp++) {
        f32x4 v = *(const f32x4*)(pOct + sp * stride + base);
        s += v;
        ls += pL[sp * lstride + lbase];
    }
    float inv = 1.0f / ls;
    u16 o[4] = {f2bf(s[0] * inv), f2bf(s[1] * inv), f2bf(s[2] * inv), f2bf(s[3] * inv)};
    *(uint2*)&ctxb[(size_t)row * 1024 + h * 64 + dq] = *(const uint2*)o;
}

// ---------------- launch ----------------
extern "C" void kernel_launch(void* const* d_in, const int* in_sizes, int n_in,
                              void* d_out, int out_size, void* d_ws, size_t ws_size,
                              hipStream_t stream) {
    (void)in_sizes; (void)n_in; (void)out_size; (void)ws_size;
    const float* x   = (const float*)d_in[0];
    const float* pgt = (const float*)d_in[1];
    const float* Wq  = (const float*)d_in[2];
    const float* bq  = (const float*)d_in[3];
    const float* Wk  = (const float*)d_in[4];
    const float* bk  = (const float*)d_in[5];
    const float* Wv  = (const float*)d_in[6];
    const float* bv  = (const float*)d_in[7];
    const float* Wo  = (const float*)d_in[8];
    const float* bo  = (const float*)d_in[9];
    const float* ln1g = (const float*)d_in[10];
    const float* ln1b = (const float*)d_in[11];
    const float* W1  = (const float*)d_in[12];
    const float* b1  = (const float*)d_in[13];
    const float* W2  = (const float*)d_in[14];
    const float* b2  = (const float*)d_in[15];
    const float* lnfg = (const float*)d_in[16];
    const float* lnfb = (const float*)d_in[17];
    const int* kvidx = (const int*)d_in[20];

    float* out = (float*)d_out;
    float* out_x  = out;
    float* out_lr = out + 2048 * 1024;
    float* out_pt = out + 2 * 2048 * 1024;

    char* ws = (char*)d_ws;
    size_t off = 0;
    auto alloc = [&](size_t bytes) { void* p = ws + off; off += (bytes + 255) & ~(size_t)255; return p; };
    u16* WqkvT = (u16*)alloc((size_t)3072 * 1024 * 2);
    u16* WoT   = (u16*)alloc((size_t)1024 * 1024 * 2);
    u16* W1T   = (u16*)alloc((size_t)4096 * 1024 * 2);
    u16* W2T   = (u16*)alloc((size_t)1024 * 4096 * 2);
    u16* xb    = (u16*)alloc((size_t)2048 * 1024 * 2);
    u16* qbuf  = (u16*)alloc((size_t)2048 * 1024 * 2);
    u16* ctxb  = (u16*)alloc((size_t)2048 * 1024 * 2);
    char* regB = (char*)alloc((size_t)168 * 1024 * 1024);
    // attn phase
    u16* Kbf  = (u16*)regB;
    u16* Vtbf = (u16*)(regB + (size_t)64 * 1024 * 1024);
    float* pOct = (float*)(regB + (size_t)128 * 1024 * 1024);   // 32 MiB
    float* pL   = (float*)(regB + (size_t)162 * 1024 * 1024);
    // FFN phase aliases
    float* p0    = (float*)regB;                                 // WO partials (16 MiB)
    float* xln1f = (float*)(regB + (size_t)16 * 1024 * 1024);
    u16*   xln1b = (u16*)(regB + (size_t)24 * 1024 * 1024);
    u16*   hb    = (u16*)(regB + (size_t)32 * 1024 * 1024);      // 16 MiB
    float* q0    = (float*)(regB + (size_t)128 * 1024 * 1024);   // FFN2 partials (32 MiB)

    prep_wx<<<4096, 256, 0, stream>>>(Wq, Wk, Wv, x, WqkvT, xb);
    mega_prep<<<10560, 256, 0, stream>>>(xb, WqkvT, bq, bk, bv,
                                         out_pt, qbuf, Kbf, Vtbf, pgt, kvidx,
                                         Wo, W1, W2, WoT, W1T, W2T);
    attn_kernel<<<1024, 512, 0, stream>>>(qbuf, Kbf, Vtbf, pOct, pL);
    attn_combine<<<2048, 256, 0, stream>>>(pOct, pL, ctxb);
    // WO split-K x2: 256 blocks -> raw partials p0/p1
    gemm_nt<MODE_WO><<<256, 256, 0, stream>>>(ctxb, WoT, 1024, 512, 1024, 8, 128,
        nullptr, p0, nullptr, (size_t)2048 * 1024);
    ln_wo<<<2048, 256, 0, stream>>>(p0, p0 + (size_t)2048 * 1024, bo, x,
                                    ln1g, ln1b, xln1f, xln1b);
    gemm_nt<MODE_F1><<<512, 256, 0, stream>>>(xln1b, W1T, 1024, 1024, 4096, 32, 512,
        b1, nullptr, hb, 0);
    // FFN2 split-K x4: 512 blocks -> raw partials q0..q3
    gemm_nt<MODE_F2><<<512, 256, 0, stream>>>(hb, W2T, 4096, 1024, 1024, 8, 128,
        nullptr, q0, nullptr, (size_t)2048 * 1024);
    ln_f2<<<2048, 256, 0, stream>>>(q0, b2, xln1f, lnfg, lnfb, out_lr, out_x);
}

// Round 12
// 330.683 us; speedup vs baseline: 1.3300x; 1.0237x over previous
//
#include <hip/hip_runtime.h>
#include <hip/hip_bf16.h>

typedef unsigned short u16;
typedef __attribute__((ext_vector_type(4))) float f32x4;
typedef __attribute__((ext_vector_type(8))) short short8;

// B=8 QLEN=256 D=1024 H=16 HD=64 FFN=4096 PAGE=16 KV_TOTAL=4096 P=256
// PREFIX=3840 SCALE=0.125
#define MODE_QKV 0
#define MODE_WO  1
#define MODE_F1  2
#define MODE_F2  3

__device__ inline u16 f2bf(float f) {
    __hip_bfloat16 h = __float2bfloat16(f);
    return *(u16*)&h;
}

typedef __attribute__((address_space(3))) unsigned int lds_u32_t;
typedef const __attribute__((address_space(1))) unsigned int glb_u32_t;
__device__ inline void gload16(const u16* g, u16* l) {
    __builtin_amdgcn_global_load_lds((glb_u32_t*)(const void*)g,
                                     (lds_u32_t*)(void*)l, 16, 0, 0);
}

// ---------------- prep: Wq/Wk/Wv transposes + x cast ----------------
__global__ __launch_bounds__(256) void prep_wx(
    const float* __restrict__ Wq, const float* __restrict__ Wk,
    const float* __restrict__ Wv, const float* __restrict__ x,
    u16* __restrict__ WqkvT, u16* __restrict__ xb) {
    int bid = blockIdx.x;
    int tid = threadIdx.x;
    int tx = tid & 31, ty = tid >> 5;
    if (bid >= 3072) {
        int i = (bid - 3072) * 256 + tid;
        const float4* p = (const float4*)(x + (size_t)i * 8);
        float4 a = p[0], b = p[1];
        u16 t[8] = {f2bf(a.x), f2bf(a.y), f2bf(a.z), f2bf(a.w),
                    f2bf(b.x), f2bf(b.y), f2bf(b.z), f2bf(b.w)};
        *(uint4*)(xb + (size_t)i * 8) = *(const uint4*)t;
        return;
    }
    int m = bid >> 10, r = bid & 1023;
    const float* src = (m == 0) ? Wq : (m == 1) ? Wk : Wv;
    u16* dst = WqkvT + (size_t)m * 1024 * 1024;
    __shared__ float t[32][33];
    int n0 = (r & 31) * 32, k0 = (r >> 5) * 32;
#pragma unroll
    for (int j = 0; j < 32; j += 8)
        t[ty + j][tx] = src[(size_t)(k0 + ty + j) * 1024 + n0 + tx];
    __syncthreads();
#pragma unroll
    for (int j = 0; j < 32; j += 8)
        dst[(size_t)(n0 + ty + j) * 1024 + k0 + tx] = f2bf(t[tx][ty + j]);
}

// ---------------- LN after WO: t = p0+p1+bo+resid; LN -> xln1f, xln1b ------------
__global__ __launch_bounds__(256) void ln_wo(const float* __restrict__ p0,
                                             const float* __restrict__ p1,
                                             const float* __restrict__ bo,
                                             const float* __restrict__ resid,
                                             const float* __restrict__ g,
                                             const float* __restrict__ be,
                                             float* __restrict__ outf,
                                             u16* __restrict__ outb) {
    int row = blockIdx.x;
    int tid = threadIdx.x;
    int c = tid * 4;
    size_t o = (size_t)row * 1024 + c;
    f32x4 v = *(const f32x4*)(p0 + o) + *(const f32x4*)(p1 + o)
            + *(const f32x4*)(bo + c) + *(const f32x4*)(resid + o);
    float s = v[0] + v[1] + v[2] + v[3];
#pragma unroll
    for (int m = 1; m < 64; m <<= 1) s += __shfl_xor(s, m, 64);
    __shared__ float red1[4], red2[4];
    int w = tid >> 6;
    if ((tid & 63) == 0) red1[w] = s;
    __syncthreads();
    float mu = (red1[0] + red1[1] + red1[2] + red1[3]) * (1.0f / 1024.0f);
    f32x4 d = v - mu;
    float q = d[0] * d[0] + d[1] * d[1] + d[2] * d[2] + d[3] * d[3];
#pragma unroll
    for (int m = 1; m < 64; m <<= 1) q += __shfl_xor(q, m, 64);
    if ((tid & 63) == 0) red2[w] = q;
    __syncthreads();
    float var = (red2[0] + red2[1] + red2[2] + red2[3]) * (1.0f / 1024.0f);
    float rs = rsqrtf(var + 1e-5f);
    f32x4 gg = *(const f32x4*)(g + c), bb = *(const f32x4*)(be + c);
    f32x4 ov = d * rs * gg + bb;
    *(f32x4*)(outf + o) = ov;
    u16 t[4] = {f2bf(ov[0]), f2bf(ov[1]), f2bf(ov[2]), f2bf(ov[3])};
    *(uint2*)&outb[o] = *(const uint2*)t;
}

// ------- final LN: lr = q0+q1+q2+q3+b2 -> out_lr; LN(lr + xln1f) -> out_x --------
__global__ __launch_bounds__(256) void ln_f2(const float* __restrict__ q0,
                                             const float* __restrict__ b2,
                                             const float* __restrict__ xln1f,
                                             const float* __restrict__ g,
                                             const float* __restrict__ be,
                                             float* __restrict__ out_lr,
                                             float* __restrict__ out_x) {
    int row = blockIdx.x;
    int tid = threadIdx.x;
    int c = tid * 4;
    size_t o = (size_t)row * 1024 + c;
    const size_t st = (size_t)2048 * 1024;
    f32x4 v = *(const f32x4*)(q0 + o) + *(const f32x4*)(q0 + st + o)
            + *(const f32x4*)(q0 + 2 * st + o) + *(const f32x4*)(q0 + 3 * st + o)
            + *(const f32x4*)(b2 + c);
    *(f32x4*)(out_lr + o) = v;
    v = v + *(const f32x4*)(xln1f + o);
    float s = v[0] + v[1] + v[2] + v[3];
#pragma unroll
    for (int m = 1; m < 64; m <<= 1) s += __shfl_xor(s, m, 64);
    __shared__ float red1[4], red2[4];
    int w = tid >> 6;
    if ((tid & 63) == 0) red1[w] = s;
    __syncthreads();
    float mu = (red1[0] + red1[1] + red1[2] + red1[3]) * (1.0f / 1024.0f);
    f32x4 d = v - mu;
    float q = d[0] * d[0] + d[1] * d[1] + d[2] * d[2] + d[3] * d[3];
#pragma unroll
    for (int m = 1; m < 64; m <<= 1) q += __shfl_xor(q, m, 64);
    if ((tid & 63) == 0) red2[w] = q;
    __syncthreads();
    float var = (red2[0] + red2[1] + red2[2] + red2[3]) * (1.0f / 1024.0f);
    float rs = rsqrtf(var + 1e-5f);
    f32x4 gg = *(const f32x4*)(g + c), bb = *(const f32x4*)(be + c);
    *(f32x4*)(out_x + o) = d * rs * gg + bb;
}

// ---------------- GEMM body: tile 128x128, BK=64, row stride lda ----------------
template <int MODE>
__device__ __forceinline__ void gemm_body(
    u16* As, u16* Bs, int m0, int n0,
    const u16* __restrict__ A, const u16* __restrict__ Bt, int lda, int Kspan, int N,
    const float* __restrict__ bias0, const float* __restrict__ bias1,
    const float* __restrict__ bias2,
    float* __restrict__ o0, u16* __restrict__ ob,
    u16* __restrict__ kbf, u16* __restrict__ vbf, const int* __restrict__ kvidx) {
    int tid = threadIdx.x;
    int l = tid & 63, w = tid >> 6;
    int wr = w >> 1, wc = w & 1;
    int lr = l & 15, lg = l >> 4;
    int lrow8 = l >> 3;
    int scol = ((l & 7) ^ lrow8) << 3;
    f32x4 acc[4][4] = {};
    for (int kb = 0; kb < Kspan; kb += 64) {
#pragma unroll
        for (int p = 0; p < 4; ++p) {
            int chunk = p * 4 + w;
            int r = chunk * 8 + lrow8;
            gload16(&A[(size_t)(m0 + r) * lda + kb + scol], &As[chunk * 512]);
            gload16(&Bt[(size_t)(n0 + r) * lda + kb + scol], &Bs[chunk * 512]);
        }
        __syncthreads();
#pragma unroll
        for (int kk = 0; kk < 2; ++kk) {
            short8 a[4], b[4];
            int c0 = kk * 32 + lg * 8;
#pragma unroll
            for (int mi = 0; mi < 4; mi++) {
                int row = wr * 64 + mi * 16 + lr;
                a[mi] = *(const short8*)&As[row * 64 + (c0 ^ ((row & 7) << 3))];
            }
#pragma unroll
            for (int ni = 0; ni < 4; ni++) {
                int row = wc * 64 + ni * 16 + lr;
                b[ni] = *(const short8*)&Bs[row * 64 + (c0 ^ ((row & 7) << 3))];
            }
#pragma unroll
            for (int mi = 0; mi < 4; mi++)
#pragma unroll
                for (int ni = 0; ni < 4; ni++)
                    acc[mi][ni] = __builtin_amdgcn_mfma_f32_16x16x32_bf16(
                        a[mi], b[ni], acc[mi][ni], 0, 0, 0);
        }
        __syncthreads();
    }
#pragma unroll
    for (int mi = 0; mi < 4; mi++) {
#pragma unroll
        for (int ni = 0; ni < 4; ni++) {
#pragma unroll
            for (int r = 0; r < 4; r++) {
                int row = m0 + wr * 64 + mi * 16 + lg * 4 + r;
                int col = n0 + wc * 64 + ni * 16 + lr;
                float v = acc[mi][ni][r];
                if constexpr (MODE == MODE_QKV) {
                    int sel = col >> 10, c = col & 1023;
                    int b = row >> 8, ii = row & 255;
                    int h = (c >> 6), hd = c & 63;
                    if (sel == 0) {
                        ob[(size_t)row * 1024 + c] = f2bf((v + bias0[c]) * 0.125f);
                    } else if (sel == 1) {
                        float val = v + bias1[c];
                        int page = kvidx[b * 256 + 240 + (ii >> 4)];
                        o0[(size_t)page * 32768 + (size_t)(ii & 15) * 1024 + c] = val;
                        kbf[((size_t)(b * 16 + h) * 4096 + 3840 + ii) * 64 + hd] = f2bf(val);
                    } else {
                        float val = v + bias2[c];
                        int page = kvidx[b * 256 + 240 + (ii >> 4)];
                        o0[(size_t)page * 32768 + 16384 + (size_t)(ii & 15) * 1024 + c] = val;
                        vbf[((size_t)(b * 16 + h) * 64 + hd) * 4096 + 3840 + ii] = f2bf(val);
                    }
                } else if constexpr (MODE == MODE_F1) {
                    float t = v + bias0[col];
                    ob[(size_t)row * N + col] = f2bf(fmaxf(t, 0.0f));
                } else { // WO / F2: raw split-K partial
                    o0[(size_t)row * N + col] = v;
                }
            }
        }
    }
}

// split-K wrapper
template <int MODE>
__global__ __launch_bounds__(256) void gemm_nt(
    const u16* __restrict__ A, const u16* __restrict__ Bt,
    int lda, int Kspan, int N, int gx, int nper,
    const float* __restrict__ bias0,
    float* __restrict__ o0, u16* __restrict__ ob, size_t osplit) {
    __shared__ __align__(16) u16 smem[128 * 64 * 2];
    int bid = blockIdx.x;
    int split = bid / nper, t = bid % nper;
    gemm_body<MODE>(smem, smem + 128 * 64, (t / gx) * 128, (t % gx) * 128,
                    A + (size_t)split * Kspan, Bt + (size_t)split * Kspan,
                    lda, Kspan, N, bias0, nullptr, nullptr,
                    o0 ? o0 + (size_t)split * osplit : nullptr, ob,
                    nullptr, nullptr, nullptr);
}

// ---- mega: K-prep [0,480) + V-prep [480,960) + QKV GEMM [960,1344) ----
__global__ __launch_bounds__(256) void mega_prep(
    const u16* __restrict__ xb, const u16* __restrict__ WqkvT,
    const float* __restrict__ bq, const float* __restrict__ bk,
    const float* __restrict__ bv,
    float* __restrict__ out_pt, u16* __restrict__ qbuf,
    u16* __restrict__ Kbf, u16* __restrict__ Vtbf,
    const float* __restrict__ pgt, const int* __restrict__ kvidx) {
    __shared__ __align__(16) u16 smem[128 * 64 * 2];
    int bid = blockIdx.x;
    int tid = threadIdx.x;
    if (bid < 480) {
        // ---- K-prep: 64 tokens x all heads; sequential page reads; f32 copy + bf16 ----
        int tile = bid % 60, b = bid / 60;
        int T0 = tile * 64;
        int h = tid >> 4, hd0 = (tid & 15) * 4;
        int pg[4];
#pragma unroll
        for (int pi = 0; pi < 4; ++pi) pg[pi] = kvidx[b * 256 + (T0 >> 4) + pi];
#pragma unroll 4
        for (int it2 = 0; it2 < 64; ++it2) {
            int pi = it2 >> 4, it = it2 & 15;
            const float* src = pgt + (size_t)pg[pi] * 32768;
            float* dst = out_pt + (size_t)pg[pi] * 32768;
            size_t o = (size_t)it * 1024 + tid * 4;
            float4 f = *(const float4*)(src + o);
            *(float4*)(dst + o) = f;
            u16 k4[4] = {f2bf(f.x), f2bf(f.y), f2bf(f.z), f2bf(f.w)};
            size_t kdst = ((size_t)(b * 16 + h) * 4096 + T0 + pi * 16 + it) * 64 + hd0;
            *(uint2*)&Kbf[kdst] = *(const uint2*)k4;
        }
        return;
    }
    if (bid < 960) {
        // ---- V-prep: 64 tokens x 2 heads per chunk (8 chunks), LDS transpose ----
        int vb2 = bid - 480;
        int tile = vb2 % 60, b = vb2 / 60;
        int T0 = tile * 64;
        int pg[4];
#pragma unroll
        for (int pi = 0; pi < 4; ++pi) pg[pi] = kvidx[b * 256 + (T0 >> 4) + pi];
        u16* vt = smem; // [64][134]
        for (int hb2 = 0; hb2 < 8; ++hb2) {
#pragma unroll 4
            for (int it = 0; it < 8; ++it) {
                int ti = it * 8 + (tid >> 5);
                int pi = ti >> 4, tokloc = ti & 15;
                int c4 = (tid & 31) * 4;
                size_t o = (size_t)pg[pi] * 32768 + 16384 + (size_t)tokloc * 1024
                           + hb2 * 128 + c4;
                float4 v = *(const float4*)(pgt + o);
                *(float4*)(out_pt + o) = v;
                u16 v4[4] = {f2bf(v.x), f2bf(v.y), f2bf(v.z), f2bf(v.w)};
                *(uint2*)&vt[ti * 134 + c4] = *(const uint2*)v4;
            }
            __syncthreads();
            int g = tid >> 4, j = tid & 15;
#pragma unroll
            for (int rp = 0; rp < 8; ++rp) {
                int ri = rp * 16 + g;
                int h = hb2 * 2 + (ri >> 6), hd = ri & 63;
                u16 o4[4];
#pragma unroll
                for (int s = 0; s < 4; ++s) o4[s] = vt[(j * 4 + s) * 134 + ri];
                *(uint2*)&Vtbf[((size_t)(b * 16 + h) * 64 + hd) * 4096 + T0 + j * 4] =
                    *(const uint2*)o4;
            }
            __syncthreads();
        }
        return;
    }
    int t = bid - 960;
    gemm_body<MODE_QKV>(smem, smem + 8192, (t / 24) * 128, (t % 24) * 128,
                        xb, WqkvT, 1024, 1024, 3072, bq, bk, bv,
                        out_pt, qbuf, Kbf, Vtbf, kvidx);
}

// ---- attention (1024 blocks) + Wo/W1/W2 transposes (4608 blocks x 2 tiles) ----
__global__ __launch_bounds__(512) void attn_kernel(const u16* __restrict__ qb,
                                                   const u16* __restrict__ Kbf,
                                                   const u16* __restrict__ Vtbf,
                                                   float* __restrict__ pOct,
                                                   float* __restrict__ pL,
                                                   const float* __restrict__ Wo,
                                                   const float* __restrict__ W1,
                                                   const float* __restrict__ W2,
                                                   u16* __restrict__ WoT,
                                                   u16* __restrict__ W1T,
                                                   u16* __restrict__ W2T) {
    __shared__ u16 Ks[64 * 64];
    __shared__ u16 Vt[64 * 64];
    __shared__ u16 Ps[8][16 * 64];
    int bid = blockIdx.x;
    int tid = threadIdx.x;
    if (bid >= 1024) {
        // ---- weight transposes: 2 x 32x32 tiles per block ----
        int sub = tid >> 8, t2 = tid & 255;
        int wb = (bid - 1024) * 2 + sub;   // 0..9215
        const float* src; u16* dst; int K, N, bx, by;
        if (wb < 1024) {
            bx = wb & 31; by = wb >> 5; K = 1024; N = 1024; src = Wo; dst = WoT;
        } else if (wb < 5120) {
            int r = wb - 1024; bx = r & 127; by = r >> 7; K = 1024; N = 4096; src = W1; dst = W1T;
        } else {
            int r = wb - 5120; bx = r & 31; by = r >> 5; K = 4096; N = 1024; src = W2; dst = W2T;
        }
        float* t = sub ? (float*)Vt : (float*)Ks;   // each 8KB >= 4224B
        int tx = t2 & 31, ty = t2 >> 5;
        int n0 = bx * 32, k0 = by * 32;
#pragma unroll
        for (int jj = 0; jj < 32; jj += 8)
            t[(ty + jj) * 33 + tx] = src[(size_t)(k0 + ty + jj) * N + n0 + tx];
        __syncthreads();
#pragma unroll
        for (int jj = 0; jj < 32; jj += 8)
            dst[(size_t)(n0 + ty + jj) * K + k0 + tx] = f2bf(t[tx * 33 + ty + jj]);
        return;
    }
    int l = tid & 63, w = tid >> 6;
    int lr = l & 15, lg = l >> 4;
    int x = bid & 7, qt = x >> 2, split = x & 3;
    int h = (bid >> 3) & 15, b = bid >> 7;

    int qrow = qt * 128 + w * 16 + lr;
    const u16* qptr = qb + (size_t)(b * 256 + qrow) * 1024 + h * 64 + lg * 8;
    short8 qf0 = *(const short8*)qptr;
    short8 qf1 = *(const short8*)(qptr + 32);

    const u16* kslab = Kbf + (size_t)(b * 16 + h) * 4096 * 64;
    const u16* vslab = Vtbf + (size_t)(b * 16 + h) * 64 * 4096;

    f32x4 octx[4] = {};
    f32x4 lacc = {};
    short8 ones;
#pragma unroll
    for (int jj = 0; jj < 8; jj++) ones[jj] = (short)0x3F80;

    int qbase = 3840 + qt * 128;
    int ntiles = (qbase + 128) >> 6;
    int tstart = split * 16;
    int tend = min(tstart + 16, ntiles);
    int kt0 = tstart * 64, kt1 = tend * 64;

    int srow = tid >> 3, scol8 = (tid & 7) * 8;
    int sdst = srow * 64 + (scol8 ^ ((srow & 7) << 3));
    const u16* kp = kslab + srow * 64 + scol8;
    const u16* vp = vslab + (size_t)srow * 4096 + scol8;

    uint4 kreg = *(const uint4*)(kp + (size_t)kt0 * 64);
    uint4 vreg = *(const uint4*)(vp + kt0);
    for (int kt = kt0; kt < kt1; kt += 64) {
        *(uint4*)&Ks[sdst] = kreg;
        *(uint4*)&Vt[sdst] = vreg;
        __syncthreads();
        bool hn = (kt + 64) < kt1;
        if (hn) {
            kreg = *(const uint4*)(kp + (size_t)(kt + 64) * 64);
            vreg = *(const uint4*)(vp + kt + 64);
        }
        float P[4][4];
        bool need_mask = (kt + 63 > qbase);
        __builtin_amdgcn_s_setprio(1);
#pragma unroll
        for (int ni = 0; ni < 4; ni++) {
            f32x4 s = {};
            int krow = ni * 16 + lr;
            int swz = (krow & 7) << 3;
            short8 k0 = *(const short8*)&Ks[krow * 64 + ((lg * 8) ^ swz)];
            short8 k1 = *(const short8*)&Ks[krow * 64 + ((32 + lg * 8) ^ swz)];
            s = __builtin_amdgcn_mfma_f32_16x16x32_bf16(qf0, k0, s, 0, 0, 0);
            s = __builtin_amdgcn_mfma_f32_16x16x32_bf16(qf1, k1, s, 0, 0, 0);
            if (need_mask) {
                int col = kt + ni * 16 + lr;
#pragma unroll
                for (int r = 0; r < 4; r++) {
                    int q = qt * 128 + w * 16 + lg * 4 + r;
                    P[ni][r] = (col <= 3840 + q) ? __expf(s[r]) : 0.0f;
                }
            } else {
#pragma unroll
                for (int r = 0; r < 4; r++) P[ni][r] = __expf(s[r]);
            }
        }
        __builtin_amdgcn_s_setprio(0);
#pragma unroll
        for (int ni = 0; ni < 4; ni++)
#pragma unroll
            for (int r = 0; r < 4; r++) {
                int prow = lg * 4 + r;
                Ps[w][prow * 64 + ((ni * 16 + lr) ^ ((prow & 7) << 3))] = f2bf(P[ni][r]);
            }
        __builtin_amdgcn_s_setprio(1);
#pragma unroll
        for (int kk = 0; kk < 2; kk++) {
            int c0 = kk * 32 + lg * 8;
            short8 pf = *(const short8*)&Ps[w][lr * 64 + (c0 ^ ((lr & 7) << 3))];
            lacc = __builtin_amdgcn_mfma_f32_16x16x32_bf16(pf, ones, lacc, 0, 0, 0);
#pragma unroll
            for (int dt = 0; dt < 4; dt++) {
                int vrow = dt * 16 + lr;
                short8 vf = *(const short8*)&Vt[vrow * 64 + (c0 ^ ((vrow & 7) << 3))];
                octx[dt] = __builtin_amdgcn_mfma_f32_16x16x32_bf16(pf, vf, octx[dt], 0, 0, 0);
            }
        }
        __builtin_amdgcn_s_setprio(0);
        __syncthreads();
    }
    size_t obase = (((size_t)(split * 8 + b) * 16 + h) * 256 + qt * 128) * 64;
#pragma unroll
    for (int dt = 0; dt < 4; dt++)
#pragma unroll
        for (int r = 0; r < 4; r++)
            pOct[obase + (size_t)(w * 16 + lg * 4 + r) * 64 + dt * 16 + lr] = octx[dt][r];
    if (lr == 0) {
        size_t lbase = ((size_t)(split * 8 + b) * 16 + h) * 256 + qt * 128;
#pragma unroll
        for (int r = 0; r < 4; r++) pL[lbase + w * 16 + lg * 4 + r] = lacc[r];
    }
}

// ---------------- combine partials -> ctx bf16 ----------------
__global__ __launch_bounds__(256) void attn_combine(const float* __restrict__ pOct,
                                                    const float* __restrict__ pL,
                                                    u16* __restrict__ ctxb) {
    int row = blockIdx.x;
    int b = row >> 8, q = row & 255;
    int tid = threadIdx.x;
    int h = tid >> 4, dq = (tid & 15) * 4;
    size_t stride = (size_t)128 * 256 * 64;
    size_t base = ((size_t)(b * 16 + h) * 256 + q) * 64 + dq;
    size_t lstride = 128 * 256;
    size_t lbase = (size_t)(b * 16 + h) * 256 + q;
    f32x4 s = {};
    float ls = 0.0f;
#pragma unroll
    for (int sp = 0; sp < 4; sp++) {
        f32x4 v = *(const f32x4*)(pOct + sp * stride + base);
        s += v;
        ls += pL[sp * lstride + lbase];
    }
    float inv = 1.0f / ls;
    u16 o[4] = {f2bf(s[0] * inv), f2bf(s[1] * inv), f2bf(s[2] * inv), f2bf(s[3] * inv)};
    *(uint2*)&ctxb[(size_t)row * 1024 + h * 64 + dq] = *(const uint2*)o;
}

// ---------------- launch ----------------
extern "C" void kernel_launch(void* const* d_in, const int* in_sizes, int n_in,
                              void* d_out, int out_size, void* d_ws, size_t ws_size,
                              hipStream_t stream) {
    (void)in_sizes; (void)n_in; (void)out_size; (void)ws_size;
    const float* x   = (const float*)d_in[0];
    const float* pgt = (const float*)d_in[1];
    const float* Wq  = (const float*)d_in[2];
    const float* bq  = (const float*)d_in[3];
    const float* Wk  = (const float*)d_in[4];
    const float* bk  = (const float*)d_in[5];
    const float* Wv  = (const float*)d_in[6];
    const float* bv  = (const float*)d_in[7];
    const float* Wo  = (const float*)d_in[8];
    const float* bo  = (const float*)d_in[9];
    const float* ln1g = (const float*)d_in[10];
    const float* ln1b = (const float*)d_in[11];
    const float* W1  = (const float*)d_in[12];
    const float* b1  = (const float*)d_in[13];
    const float* W2  = (const float*)d_in[14];
    const float* b2  = (const float*)d_in[15];
    const float* lnfg = (const float*)d_in[16];
    const float* lnfb = (const float*)d_in[17];
    const int* kvidx = (const int*)d_in[20];

    float* out = (float*)d_out;
    float* out_x  = out;
    float* out_lr = out + 2048 * 1024;
    float* out_pt = out + 2 * 2048 * 1024;

    char* ws = (char*)d_ws;
    size_t off = 0;
    auto alloc = [&](size_t bytes) { void* p = ws + off; off += (bytes + 255) & ~(size_t)255; return p; };
    u16* WqkvT = (u16*)alloc((size_t)3072 * 1024 * 2);
    u16* WoT   = (u16*)alloc((size_t)1024 * 1024 * 2);
    u16* W1T   = (u16*)alloc((size_t)4096 * 1024 * 2);
    u16* W2T   = (u16*)alloc((size_t)1024 * 4096 * 2);
    u16* xb    = (u16*)alloc((size_t)2048 * 1024 * 2);
    u16* qbuf  = (u16*)alloc((size_t)2048 * 1024 * 2);
    u16* ctxb  = (u16*)alloc((size_t)2048 * 1024 * 2);
    char* regB = (char*)alloc((size_t)168 * 1024 * 1024);
    // attn phase
    u16* Kbf  = (u16*)regB;
    u16* Vtbf = (u16*)(regB + (size_t)64 * 1024 * 1024);
    float* pOct = (float*)(regB + (size_t)128 * 1024 * 1024);
    float* pL   = (float*)(regB + (size_t)162 * 1024 * 1024);
    // FFN phase aliases
    float* p0    = (float*)regB;
    float* xln1f = (float*)(regB + (size_t)16 * 1024 * 1024);
    u16*   xln1b = (u16*)(regB + (size_t)24 * 1024 * 1024);
    u16*   hb    = (u16*)(regB + (size_t)32 * 1024 * 1024);
    float* q0    = (float*)(regB + (size_t)128 * 1024 * 1024);

    prep_wx<<<4096, 256, 0, stream>>>(Wq, Wk, Wv, x, WqkvT, xb);
    mega_prep<<<1344, 256, 0, stream>>>(xb, WqkvT, bq, bk, bv,
                                        out_pt, qbuf, Kbf, Vtbf, pgt, kvidx);
    attn_kernel<<<5632, 512, 0, stream>>>(qbuf, Kbf, Vtbf, pOct, pL,
                                          Wo, W1, W2, WoT, W1T, W2T);
    attn_combine<<<2048, 256, 0, stream>>>(pOct, pL, ctxb);
    gemm_nt<MODE_WO><<<256, 256, 0, stream>>>(ctxb, WoT, 1024, 512, 1024, 8, 128,
        nullptr, p0, nullptr, (size_t)2048 * 1024);
    ln_wo<<<2048, 256, 0, stream>>>(p0, p0 + (size_t)2048 * 1024, bo, x,
                                    ln1g, ln1b, xln1f, xln1b);
    gemm_nt<MODE_F1><<<512, 256, 0, stream>>>(xln1b, W1T, 1024, 1024, 4096, 32, 512,
        b1, nullptr, hb, 0);
    gemm_nt<MODE_F2><<<512, 256, 0, stream>>>(hb, W2T, 4096, 1024, 1024, 8, 128,
        nullptr, q0, nullptr, (size_t)2048 * 1024);
    ln_f2<<<2048, 256, 0, stream>>>(q0, b2, xln1f, lnfg, lnfb, out_lr, out_x);
}